// Round 2
// baseline (1653.609 us; speedup 1.0000x reference)
//
#include <hip/hip_runtime.h>
#include <math.h>

#define NTH 1024

__device__ __forceinline__ float wsum(float v) {
#pragma unroll
  for (int off = 32; off > 0; off >>= 1) v += __shfl_xor(v, off, 64);
  return v;
}

// Generic row-grouped matvec: units (o, g), g in 0..3, rows r0=g*5..+4.
// out[r*ostride + o] = act(bias[o] + sum_k in[r*K+k] * W[o*K + k])
template <int N, int K, int RELU>
__device__ __forceinline__ void mvg4(const float* __restrict__ W,
                                     const float* __restrict__ bias,
                                     const float* __restrict__ in,
                                     float* __restrict__ outp, int ostride,
                                     int tid) {
  constexpr int UNITS = N * 4;
  for (int u = tid; u < UNITS; u += NTH) {
    const int g = u / N;
    const int o = u - g * N;
    const int r0 = g * 5;
    float acc[5];
    const float bv = bias[o];
#pragma unroll
    for (int r = 0; r < 5; ++r) acc[r] = bv;
    const float4* wrow = (const float4*)(W + (size_t)o * K);
    const float* inb = in + r0 * K;
    for (int k4 = 0; k4 < K / 4; ++k4) {
      float4 w = wrow[k4];
#pragma unroll
      for (int r = 0; r < 5; ++r) {
        float4 hv = *(const float4*)(inb + r * K + k4 * 4);
        acc[r] = fmaf(hv.x, w.x, acc[r]);
        acc[r] = fmaf(hv.y, w.y, acc[r]);
        acc[r] = fmaf(hv.z, w.z, acc[r]);
        acc[r] = fmaf(hv.w, w.w, acc[r]);
      }
    }
#pragma unroll
    for (int r = 0; r < 5; ++r) {
      float v = acc[r];
      if (RELU) v = fmaxf(v, 0.f);
      outp[(r0 + r) * ostride + o] = v;
    }
  }
}

// in-place LayerNorm over rows of H (20 x 256); optional residual add[r*256+d]
__device__ __forceinline__ void ln20(float (*H)[256], const float* __restrict__ add,
                                     const float* __restrict__ g,
                                     const float* __restrict__ bt, int tid) {
  const int lane = tid & 63;
  const int wv = tid >> 6;  // 0..15
  const int d0 = lane * 4;
  for (int r = wv; r < 20; r += 16) {
    float xv[4];
#pragma unroll
    for (int j = 0; j < 4; ++j) {
      xv[j] = H[r][d0 + j];
      if (add) xv[j] += add[r * 256 + d0 + j];
    }
    float m = wsum(xv[0] + xv[1] + xv[2] + xv[3]) * (1.f / 256.f);
    float c0 = xv[0] - m, c1 = xv[1] - m, c2 = xv[2] - m, c3 = xv[3] - m;
    float var = wsum(c0 * c0 + c1 * c1 + c2 * c2 + c3 * c3) * (1.f / 256.f);
    float inv = rsqrtf(var + 1e-5f);
    H[r][d0 + 0] = c0 * inv * g[d0 + 0] + bt[d0 + 0];
    H[r][d0 + 1] = c1 * inv * g[d0 + 1] + bt[d0 + 1];
    H[r][d0 + 2] = c2 * inv * g[d0 + 2] + bt[d0 + 2];
    H[r][d0 + 3] = c3 * inv * g[d0 + 3] + bt[d0 + 3];
  }
}

__global__ __launch_bounds__(NTH, 1) void aai_tail(
    const float* __restrict__ x, const float* __restrict__ c1w,
    const float* __restrict__ c1b, const float* __restrict__ c2w,
    const float* __restrict__ c2b, const float* __restrict__ lnfg,
    const float* __restrict__ lnfb, const float* __restrict__ tw,
    const float* __restrict__ tb, const float* __restrict__ sw,
    const float* __restrict__ sb, const float* __restrict__ aiw,
    const float* __restrict__ aib, const float* __restrict__ aow,
    const float* __restrict__ aob, const float* __restrict__ l1g,
    const float* __restrict__ l1b, const float* __restrict__ f1w,
    const float* __restrict__ f1b, const float* __restrict__ f2w,
    const float* __restrict__ f2b, const float* __restrict__ l2g,
    const float* __restrict__ l2b, const float* __restrict__ fcw,
    const float* __restrict__ fcb, float* __restrict__ out) {
  __shared__ float xs[24][16];      // x[t=3977..3999], row 23 = 0 (t=4000 pad)
  __shared__ float h[20][256];      // main state, tokens t=3980..3999
  __shared__ float bb[20][256];     // scratch (attn-o / ff2-out / trend+season)
  __shared__ float tmp[20 * 1024];  // c1[22][256] / qkv[20][768]+scores / ff1[20][1024]

  const int tid = threadIdx.x;
  const int b = blockIdx.x;

  // ---- stage: load x tail slice
  for (int i = tid; i < 24 * 16; i += NTH) {
    int r = i >> 4, c = i & 15;
    xs[r][c] = (r < 23) ? x[((size_t)b * 4000 + 3977 + r) * 16 + c] : 0.f;
  }
  __syncthreads();

  // ---- conv1 + ReLU: c1 rows 0..20 = t 3979..3999; row 21 = 0 (t=4000)
  float* c1 = tmp;  // [22][256]
  {
    const int d = tid & 255;
    const int g = tid >> 8;
    const int r0 = g * 5;
    const int cnt = (g == 3) ? 6 : 5;
    const float* wr = c1w + d * 48;
    float acc[6];
    const float bv = c1b[d];
#pragma unroll
    for (int r = 0; r < 6; ++r) acc[r] = bv;
    for (int c = 0; c < 16; ++c) {
      float w0 = wr[c * 3], w1 = wr[c * 3 + 1], w2 = wr[c * 3 + 2];
#pragma unroll
      for (int r = 0; r < 6; ++r)
        acc[r] += xs[r0 + r + 1][c] * w0 + xs[r0 + r + 2][c] * w1 +
                  xs[r0 + r + 3][c] * w2;
    }
    for (int r = 0; r < cnt; ++r) c1[(r0 + r) * 256 + d] = fmaxf(acc[r], 0.f);
    if (g == 0) c1[21 * 256 + d] = 0.f;
  }
  __syncthreads();

  // ---- conv2 + ReLU -> h (pre-LN), rows = t 3980..3999
  {
    const int d = tid & 255;
    const int g = tid >> 8;
    const int r0 = g * 5;
    const float4* wr4 = (const float4*)(c2w + (size_t)d * 768);
    float acc[5];
    const float bv = c2b[d];
#pragma unroll
    for (int r = 0; r < 5; ++r) acc[r] = bv;
    for (int e4 = 0; e4 < 64; ++e4) {
      float4 f0 = wr4[e4 * 3 + 0];
      float4 f1 = wr4[e4 * 3 + 1];
      float4 f2 = wr4[e4 * 3 + 2];
      float4 cl[7];
#pragma unroll
      for (int i = 0; i < 7; ++i)
        cl[i] = *(const float4*)(c1 + (r0 + i) * 256 + e4 * 4);
#pragma unroll
      for (int r = 0; r < 5; ++r) {
        float a = acc[r];
        a = fmaf(cl[r].x, f0.x, a); a = fmaf(cl[r + 1].x, f0.y, a); a = fmaf(cl[r + 2].x, f0.z, a);
        a = fmaf(cl[r].y, f0.w, a); a = fmaf(cl[r + 1].y, f1.x, a); a = fmaf(cl[r + 2].y, f1.y, a);
        a = fmaf(cl[r].z, f1.z, a); a = fmaf(cl[r + 1].z, f1.w, a); a = fmaf(cl[r + 2].z, f2.x, a);
        a = fmaf(cl[r].w, f2.y, a); a = fmaf(cl[r + 1].w, f2.z, a); a = fmaf(cl[r + 2].w, f2.w, a);
        acc[r] = a;
      }
    }
#pragma unroll
    for (int r = 0; r < 5; ++r) h[r0 + r][d] = fmaxf(acc[r], 0.f);
  }
  __syncthreads();

  // ---- LayerNorm_f (in place)
  ln20(h, nullptr, lnfg, lnfb, tid);
  __syncthreads();

  // ---- trend + season: bb = (h@tw.T + tb) + sin(h@sw.T + sb); then h += bb
  {
    const int d = tid & 255;
    const int g = tid >> 8;
    const int r0 = g * 5;
    float at[5], as[5];
    const float tbv = tb[d], sbv = sb[d];
#pragma unroll
    for (int r = 0; r < 5; ++r) { at[r] = tbv; as[r] = sbv; }
    const float4* twr = (const float4*)(tw + d * 256);
    const float4* swr = (const float4*)(sw + d * 256);
    for (int k4 = 0; k4 < 64; ++k4) {
      float4 wt = twr[k4];
      float4 ws = swr[k4];
#pragma unroll
      for (int r = 0; r < 5; ++r) {
        float4 hv = *(const float4*)(&h[r0 + r][k4 * 4]);
        at[r] += hv.x * wt.x + hv.y * wt.y + hv.z * wt.z + hv.w * wt.w;
        as[r] += hv.x * ws.x + hv.y * ws.y + hv.z * ws.z + hv.w * ws.w;
      }
    }
#pragma unroll
    for (int r = 0; r < 5; ++r) bb[r0 + r][d] = at[r] + sinf(as[r]);
  }
  __syncthreads();
  for (int i = tid; i < 20 * 256; i += NTH) (&h[0][0])[i] += (&bb[0][0])[i];
  __syncthreads();

  // ---- encoder layers
  float* qkv = tmp;            // [20][768] packed r*768+e
  float* scb = tmp + 20 * 768; // scores [8][20][20]
  for (int l = 0; l < 4; ++l) {
    // qkv projection
    mvg4<768, 256, 0>(aiw + (size_t)l * 768 * 256, aib + l * 768, &h[0][0],
                      qkv, 768, tid);
    __syncthreads();
    // scores = q.k / sqrt(32)
    for (int i = tid; i < 8 * 20 * 20; i += NTH) {
      int hd = i / 400, rem = i % 400, qi = rem / 20, kj = rem % 20;
      const float4* qp = (const float4*)(qkv + qi * 768 + hd * 32);
      const float4* kp = (const float4*)(qkv + kj * 768 + 256 + hd * 32);
      float s = 0.f;
#pragma unroll
      for (int d4 = 0; d4 < 8; ++d4) {
        float4 q = qp[d4], k = kp[d4];
        s += q.x * k.x + q.y * k.y + q.z * k.z + q.w * k.w;
      }
      scb[i] = s * 0.17677669529663687f;
    }
    __syncthreads();
    // softmax over last axis (20)
    if (tid < 160) {
      float* row = scb + tid * 20;
      float m = row[0];
#pragma unroll
      for (int j = 1; j < 20; ++j) m = fmaxf(m, row[j]);
      float s = 0.f;
      float e[20];
#pragma unroll
      for (int j = 0; j < 20; ++j) { e[j] = __expf(row[j] - m); s += e[j]; }
      float inv = 1.f / s;
#pragma unroll
      for (int j = 0; j < 20; ++j) row[j] = e[j] * inv;
    }
    __syncthreads();
    // o = a @ v -> bb
    {
      const int d = tid & 255;
      const int g = tid >> 8;
      const int r0 = g * 5;
      const float* arow = scb + (d >> 5) * 400;
      float acc[5] = {0.f, 0.f, 0.f, 0.f, 0.f};
      for (int j = 0; j < 20; ++j) {
        float vv = qkv[j * 768 + 512 + d];
#pragma unroll
        for (int r = 0; r < 5; ++r) acc[r] += arow[(r0 + r) * 20 + j] * vv;
      }
#pragma unroll
      for (int r = 0; r < 5; ++r) bb[r0 + r][d] = acc[r];
    }
    __syncthreads();
    // out projection -> tmp[0..5119] as [20][256] (qkv region is dead now)
    mvg4<256, 256, 0>(aow + (size_t)l * 256 * 256, aob + l * 256, &bb[0][0],
                      tmp, 256, tid);
    __syncthreads();
    // h = LN1(h + proj)
    ln20(h, tmp, l1g + l * 256, l1b + l * 256, tid);
    __syncthreads();
    // ff1 (+ReLU) -> tmp [20][1024]
    mvg4<1024, 256, 1>(f1w + (size_t)l * 1024 * 256, f1b + l * 1024, &h[0][0],
                       tmp, 1024, tid);
    __syncthreads();
    // ff2 -> bb
    mvg4<256, 1024, 0>(f2w + (size_t)l * 256 * 1024, f2b + l * 256, tmp,
                       &bb[0][0], 256, tid);
    __syncthreads();
    // h = LN2(h + ff2)
    ln20(h, &bb[0][0], l2g + l * 256, l2b + l * 256, tid);
    __syncthreads();
  }

  // ---- final fc on last token (row 19 == t=3999): one wave per output
  {
    const int wv = tid >> 6;
    const int lane = tid & 63;
    if (wv < 16) {
      float4 hv = *(const float4*)(&h[19][lane * 4]);
      float4 wv4 = *(const float4*)(&fcw[wv * 256 + lane * 4]);
      float s = hv.x * wv4.x + hv.y * wv4.y + hv.z * wv4.z + hv.w * wv4.w;
      s = wsum(s);
      if (lane == 0) out[b * 16 + wv] = s + fcb[wv];
    }
  }
}

extern "C" void kernel_launch(void* const* d_in, const int* in_sizes, int n_in,
                              void* d_out, int out_size, void* d_ws, size_t ws_size,
                              hipStream_t stream) {
  const float* x    = (const float*)d_in[0];
  const float* c1w  = (const float*)d_in[1];
  const float* c1b  = (const float*)d_in[2];
  const float* c2w  = (const float*)d_in[3];
  const float* c2b  = (const float*)d_in[4];
  const float* lnfg = (const float*)d_in[5];
  const float* lnfb = (const float*)d_in[6];
  const float* tw   = (const float*)d_in[7];
  const float* tb   = (const float*)d_in[8];
  const float* sw   = (const float*)d_in[9];
  const float* sb   = (const float*)d_in[10];
  const float* aiw  = (const float*)d_in[11];
  const float* aib  = (const float*)d_in[12];
  const float* aow  = (const float*)d_in[13];
  const float* aob  = (const float*)d_in[14];
  const float* l1g  = (const float*)d_in[15];
  const float* l1b  = (const float*)d_in[16];
  const float* f1w  = (const float*)d_in[17];
  const float* f1b  = (const float*)d_in[18];
  const float* f2w  = (const float*)d_in[19];
  const float* f2b  = (const float*)d_in[20];
  const float* l2g  = (const float*)d_in[21];
  const float* l2b  = (const float*)d_in[22];
  const float* fcw  = (const float*)d_in[23];
  const float* fcb  = (const float*)d_in[24];
  float* out = (float*)d_out;

  aai_tail<<<32, NTH, 0, stream>>>(x, c1w, c1b, c2w, c2b, lnfg, lnfb, tw, tb,
                                   sw, sb, aiw, aib, aow, aob, l1g, l1b, f1w,
                                   f1b, f2w, f2b, l2g, l2b, fcw, fcb, out);
}

// Round 4
// 430.412 us; speedup vs baseline: 3.8419x; 3.8419x over previous
//
#include <hip/hip_runtime.h>
#include <math.h>

#define NTH 256

typedef __attribute__((ext_vector_type(8))) short short8;
typedef __attribute__((ext_vector_type(4))) float f32x4;
typedef unsigned short ushort;
typedef unsigned int uint;

#define MFMA16(a, b, c) __builtin_amdgcn_mfma_f32_16x16x32_bf16(a, b, c, 0, 0, 0)

// fp32 -> bf16 round-to-nearest-even
__device__ __forceinline__ ushort f2bf(float f) {
  uint u = __float_as_uint(f);
  u = (u + 0x7FFFu + ((u >> 16) & 1u)) >> 16;
  return (ushort)u;
}

__device__ __forceinline__ float wsum(float v) {
#pragma unroll
  for (int off = 32; off > 0; off >>= 1) v += __shfl_xor(v, off, 64);
  return v;
}

// ---- weight convert kernel: fp32 inputs -> bf16 in d_ws ------------------
#define W2R 0            // [256][768]  conv2 re-layout: w2r[o][t*256+e] = c2w[o][e*3+t]
#define TWO 196608       // [256][256]
#define SWO 262144       // [256][256]
#define QKVO 327680      // [4][768][256]
#define AOWO 1114112     // [4][256][256]
#define F1O 1376256      // [4][1024][256]
#define F2O 2424832      // [4][256][1024]
#define WTOT 3473408

__global__ void k_cvt(const float* __restrict__ c2w, const float* __restrict__ tw,
                      const float* __restrict__ sw, const float* __restrict__ aiw,
                      const float* __restrict__ aow, const float* __restrict__ f1w,
                      const float* __restrict__ f2w, ushort* __restrict__ ws) {
  for (int i = blockIdx.x * NTH + threadIdx.x; i < WTOT; i += gridDim.x * NTH) {
    float v;
    if (i < TWO) {
      int o = i / 768, k = i - o * 768;
      int t = k >> 8, e = k & 255;
      v = c2w[o * 768 + e * 3 + t];
    } else if (i < SWO) v = tw[i - TWO];
    else if (i < QKVO) v = sw[i - SWO];
    else if (i < AOWO) v = aiw[i - QKVO];
    else if (i < F1O)  v = aow[i - AOWO];
    else if (i < F2O)  v = f1w[i - F1O];
    else               v = f2w[i - F2O];
    ws[i] = f2bf(v);
  }
}

// ---- MFMA GEMM: out[20][N] = act(bias + A[20][K] * W[N][K]^T) ------------
#define M_F32 0
#define M_F32RELU 1
#define M_SINADD 2
#define M_BF16 3
#define M_BF16RELU 4
#define M_QKV 5

template <int KDIM, int NT, int MODE>
__device__ __forceinline__ void gemm20(const ushort* __restrict__ A, int lda,
                                       const ushort* __restrict__ Wg,
                                       const float* __restrict__ bias,
                                       float* __restrict__ outf,
                                       ushort* __restrict__ outb, int ostride,
                                       ushort* __restrict__ vt, int tid) {
  constexpr int NCH = KDIM / 128;
  constexpr int MY = NT / 4;
  const int lane = tid & 63;
  const int wv = tid >> 6;
  const int col = lane & 15;
  const int kg = lane >> 4;
  const int r0 = col;
  const int r1c = (16 + col > 19) ? 19 : (16 + col);

  f32x4 acc[MY][2];
#pragma unroll
  for (int i = 0; i < MY; ++i) {
    const float bv = bias[(wv + 4 * i) * 16 + col];
#pragma unroll
    for (int mt = 0; mt < 2; ++mt) acc[i][mt] = {bv, bv, bv, bv};
  }

#pragma unroll
  for (int kc = 0; kc < NCH; ++kc) {
    short8 af[2][4];
#pragma unroll
    for (int ks = 0; ks < 4; ++ks) {
      const int k0 = kc * 128 + ks * 32 + kg * 8;
      af[0][ks] = *(const short8*)(A + r0 * lda + k0);
      af[1][ks] = *(const short8*)(A + r1c * lda + k0);
    }
#pragma unroll
    for (int i = 0; i < MY; ++i) {
      const ushort* wb =
          Wg + (size_t)((wv + 4 * i) * 16 + col) * KDIM + kc * 128 + kg * 8;
#pragma unroll
      for (int ks = 0; ks < 4; ++ks) {
        short8 bf = *(const short8*)(wb + ks * 32);
        acc[i][0] = MFMA16(af[0][ks], bf, acc[i][0]);
        acc[i][1] = MFMA16(af[1][ks], bf, acc[i][1]);
      }
    }
  }

#pragma unroll
  for (int i = 0; i < MY; ++i) {
    const int og = (wv + 4 * i) * 16 + col;
#pragma unroll
    for (int mt = 0; mt < 2; ++mt) {
#pragma unroll
      for (int j = 0; j < 4; ++j) {
        const int row = mt * 16 + kg * 4 + j;
        if (row < 20) {
          float v = acc[i][mt][j];
          if (MODE == M_F32) outf[row * ostride + og] = v;
          if (MODE == M_F32RELU) outf[row * ostride + og] = fmaxf(v, 0.f);
          if (MODE == M_SINADD) outf[row * ostride + og] += sinf(v);
          if (MODE == M_BF16) outb[row * ostride + og] = f2bf(v);
          if (MODE == M_BF16RELU) outb[row * ostride + og] = f2bf(fmaxf(v, 0.f));
          if (MODE == M_QKV) {
            ushort bv = f2bf(v);
            outb[row * ostride + og] = bv;
            if (og >= 512) {  // V part -> also transposed copy vt[h][dh][token]
              int hh = (og - 512) >> 5, dh = (og - 512) & 31;
              vt[hh * 1024 + dh * 32 + row] = bv;
            }
          }
        }
      }
    }
  }
}

// in-place LayerNorm over 20 rows of H; optional residual add; writes bf16 mirror
__device__ __forceinline__ void ln20(float (*H)[256], ushort* __restrict__ hb,
                                     const float* __restrict__ add,
                                     const float* __restrict__ g,
                                     const float* __restrict__ bt, int tid) {
  const int lane = tid & 63;
  const int wv = tid >> 6;
  const int d0 = lane * 4;
  for (int r = wv; r < 20; r += 4) {
    float xv[4];
#pragma unroll
    for (int j = 0; j < 4; ++j) {
      xv[j] = H[r][d0 + j];
      if (add) xv[j] += add[r * 256 + d0 + j];
    }
    float m = wsum(xv[0] + xv[1] + xv[2] + xv[3]) * (1.f / 256.f);
    float c0 = xv[0] - m, c1 = xv[1] - m, c2 = xv[2] - m, c3 = xv[3] - m;
    float var = wsum(c0 * c0 + c1 * c1 + c2 * c2 + c3 * c3) * (1.f / 256.f);
    float inv = rsqrtf(var + 1e-5f);
#pragma unroll
    for (int j = 0; j < 4; ++j) {
      float cj = (j == 0 ? c0 : j == 1 ? c1 : j == 2 ? c2 : c3);
      float o = cj * inv * g[d0 + j] + bt[d0 + j];
      H[r][d0 + j] = o;
      hb[r * 256 + d0 + j] = f2bf(o);
    }
  }
}

__global__ __launch_bounds__(NTH, 1) void aai_main(
    const float* __restrict__ x, const float* __restrict__ c1w,
    const float* __restrict__ c1b, const float* __restrict__ c2b,
    const float* __restrict__ lnfg, const float* __restrict__ lnfb,
    const float* __restrict__ tb, const float* __restrict__ sb,
    const float* __restrict__ aib, const float* __restrict__ aob_b,
    const float* __restrict__ l1g, const float* __restrict__ l1b,
    const float* __restrict__ f1b, const float* __restrict__ f2b,
    const float* __restrict__ l2g, const float* __restrict__ l2b,
    const float* __restrict__ fcw, const float* __restrict__ fcb,
    const ushort* __restrict__ ws, float* __restrict__ out) {
  __shared__ float xs[24][16];
  __shared__ float h[20][256];
  __shared__ float bb[20][256];
  __shared__ __align__(16) ushort hb[20 * 256];
  __shared__ __align__(16) ushort qkvb[20 * 768];
  __shared__ __align__(16) ushort big[20480];  // c1[22][256] | {aob,P,vT} | ffb[20][1024]
  __shared__ float scores[8 * 20 * 20];

  const int tid = threadIdx.x;
  const int b = blockIdx.x;
  const int lane = tid & 63;
  const int wv = tid >> 6;
  const int col = lane & 15;
  const int kg = lane >> 4;
  const int r1c = (16 + col > 19) ? 19 : (16 + col);

  ushort* c1u = big;           // [22][256]
  ushort* ffb = big;           // [20][1024]
  ushort* aob = big;           // [20][256]
  ushort* Pb = big + 5120;     // [8][20][32]
  ushort* vT = big + 10240;    // [8][32][32]

  // ---- stage x tail (t = 3977..3999, row 23 = 0)
  for (int i = tid; i < 24 * 16; i += NTH) {
    int r = i >> 4, c = i & 15;
    xs[r][c] = (r < 23) ? x[((size_t)b * 4000 + 3977 + r) * 16 + c] : 0.f;
  }
  __syncthreads();

  // ---- conv1 + ReLU -> c1 bf16 (rows t=3979..3999, row 21 = t=4000 = 0)
  {
    const int d = tid;
    const float* wr = c1w + d * 48;
    float acc[21];
    const float bv = c1b[d];
#pragma unroll
    for (int r = 0; r < 21; ++r) acc[r] = bv;
    for (int c = 0; c < 16; ++c) {
      float xv[23];
#pragma unroll
      for (int i = 0; i < 23; ++i) xv[i] = xs[i + 1][c];
      float w0 = wr[c * 3], w1 = wr[c * 3 + 1], w2 = wr[c * 3 + 2];
#pragma unroll
      for (int r = 0; r < 21; ++r)
        acc[r] += xv[r] * w0 + xv[r + 1] * w1 + xv[r + 2] * w2;
    }
#pragma unroll
    for (int r = 0; r < 21; ++r) c1u[r * 256 + d] = f2bf(fmaxf(acc[r], 0.f));
    c1u[21 * 256 + d] = 0;
  }
  __syncthreads();

  // ---- conv2 + ReLU -> h fp32 (GEMM: A[r][k]=c1_flat[r*256+k], K=768)
  gemm20<768, 16, M_F32RELU>(c1u, 256, ws + W2R, c2b, &h[0][0], nullptr, 256,
                             nullptr, tid);
  __syncthreads();

  // ---- LayerNorm_f (writes h fp32 + hb bf16)
  ln20(h, hb, nullptr, lnfg, lnfb, tid);
  __syncthreads();

  // ---- trend -> bb ; season -> bb += sin(.)
  gemm20<256, 16, M_F32>(hb, 256, ws + TWO, tb, &bb[0][0], nullptr, 256,
                         nullptr, tid);
  __syncthreads();
  gemm20<256, 16, M_SINADD>(hb, 256, ws + SWO, sb, &bb[0][0], nullptr, 256,
                            nullptr, tid);
  __syncthreads();
  for (int i = tid; i < 20 * 256; i += NTH) {
    float v = (&h[0][0])[i] + (&bb[0][0])[i];
    (&h[0][0])[i] = v;
    hb[i] = f2bf(v);
  }
  __syncthreads();

  // ---- encoder layers
  for (int l = 0; l < 4; ++l) {
    // qkv projection -> qkvb bf16 [20][768] (+ V transposed into vT).
    // vT pad tokens 20..31 are NEVER written by the gemm epilogue -> zero them
    // in the same sync window (disjoint addresses; layer-0 LDS garbage there
    // can be NaN/Inf bf16 patterns and 0*Inf = NaN in the PV MFMA).
    gemm20<256, 48, M_QKV>(hb, 256, ws + QKVO + l * 196608, aib + l * 768,
                           nullptr, qkvb, 768, vT, tid);
    for (int i = tid; i < 8 * 32 * 12; i += NTH) {
      int hh = i / 384, r = i - hh * 384;
      int dh = r / 12, tk = 20 + (r - dh * 12);
      vT[hh * 1024 + dh * 32 + tk] = 0;
    }
    __syncthreads();

    // scores = Q.K^T / sqrt(32), per head via MFMA (K=32)
    for (int hh = wv; hh < 8; hh += 4) {
      short8 aq[2], bk[2];
      aq[0] = *(const short8*)(qkvb + col * 768 + hh * 32 + kg * 8);
      aq[1] = *(const short8*)(qkvb + r1c * 768 + hh * 32 + kg * 8);
      bk[0] = *(const short8*)(qkvb + col * 768 + 256 + hh * 32 + kg * 8);
      bk[1] = *(const short8*)(qkvb + r1c * 768 + 256 + hh * 32 + kg * 8);
      f32x4 dqk[2][2];
#pragma unroll
      for (int mt = 0; mt < 2; ++mt)
#pragma unroll
        for (int nt = 0; nt < 2; ++nt) {
          dqk[mt][nt] = {0.f, 0.f, 0.f, 0.f};
          dqk[mt][nt] = MFMA16(aq[mt], bk[nt], dqk[mt][nt]);
        }
#pragma unroll
      for (int mt = 0; mt < 2; ++mt)
#pragma unroll
        for (int nt = 0; nt < 2; ++nt)
#pragma unroll
          for (int j = 0; j < 4; ++j) {
            int row = mt * 16 + kg * 4 + j, kj = nt * 16 + col;
            if (row < 20 && kj < 20)
              scores[hh * 400 + row * 20 + kj] =
                  dqk[mt][nt][j] * 0.17677669529663687f;
          }
    }
    __syncthreads();

    // softmax rows -> P bf16 [8][20][32], zero-padded to K=32
    if (tid < 160) {
      const int hh = tid / 20, q = tid - hh * 20;
      const float* row = scores + hh * 400 + q * 20;
      float m = row[0];
#pragma unroll
      for (int j = 1; j < 20; ++j) m = fmaxf(m, row[j]);
      float e[20], s = 0.f;
#pragma unroll
      for (int j = 0; j < 20; ++j) { e[j] = __expf(row[j] - m); s += e[j]; }
      float inv = 1.f / s;
      ushort* pr = Pb + hh * 640 + q * 32;
#pragma unroll
      for (int j = 0; j < 20; ++j) pr[j] = f2bf(e[j] * inv);
#pragma unroll
      for (int j = 20; j < 32; ++j) pr[j] = 0;
    }
    __syncthreads();

    // O = P @ V per head via MFMA (K=32, pad K of P is zero, vT pad zeroed)
    for (int hh = wv; hh < 8; hh += 4) {
      const ushort* Ph = Pb + hh * 640;
      const ushort* Vh = vT + hh * 1024;
      short8 ap[2], bv[2];
      ap[0] = *(const short8*)(Ph + col * 32 + kg * 8);
      ap[1] = *(const short8*)(Ph + ((16 + col > 19) ? 19 : 16 + col) * 32 + kg * 8);
      bv[0] = *(const short8*)(Vh + col * 32 + kg * 8);
      bv[1] = *(const short8*)(Vh + (16 + col) * 32 + kg * 8);
      f32x4 dav[2][2];
#pragma unroll
      for (int mt = 0; mt < 2; ++mt)
#pragma unroll
        for (int nt = 0; nt < 2; ++nt) {
          dav[mt][nt] = {0.f, 0.f, 0.f, 0.f};
          dav[mt][nt] = MFMA16(ap[mt], bv[nt], dav[mt][nt]);
        }
#pragma unroll
      for (int mt = 0; mt < 2; ++mt)
#pragma unroll
        for (int nt = 0; nt < 2; ++nt)
#pragma unroll
          for (int j = 0; j < 4; ++j) {
            int row = mt * 16 + kg * 4 + j, dc = nt * 16 + col;
            if (row < 20) aob[row * 256 + hh * 32 + dc] = f2bf(dav[mt][nt][j]);
          }
    }
    __syncthreads();

    // out projection -> bb fp32
    gemm20<256, 16, M_F32>(aob, 256, ws + AOWO + l * 65536, aob_b + l * 256,
                           &bb[0][0], nullptr, 256, nullptr, tid);
    __syncthreads();
    // h = LN1(h + proj)
    ln20(h, hb, &bb[0][0], l1g + l * 256, l1b + l * 256, tid);
    __syncthreads();
    // ff1 + ReLU -> ffb bf16 [20][1024]
    gemm20<256, 64, M_BF16RELU>(hb, 256, ws + F1O + l * 262144, f1b + l * 1024,
                                nullptr, ffb, 1024, nullptr, tid);
    __syncthreads();
    // ff2 -> bb fp32
    gemm20<1024, 16, M_F32>(ffb, 1024, ws + F2O + l * 262144, f2b + l * 256,
                            &bb[0][0], nullptr, 256, nullptr, tid);
    __syncthreads();
    // h = LN2(h + ff)
    ln20(h, hb, &bb[0][0], l2g + l * 256, l2b + l * 256, tid);
    __syncthreads();
  }

  // ---- final fc on last token (row 19), fp32
  if (tid < 16) {
    const float* wr = fcw + tid * 256;
    float s = fcb[tid];
    for (int d = 0; d < 256; ++d) s += h[19][d] * wr[d];
    out[b * 16 + tid] = s;
  }
}

extern "C" void kernel_launch(void* const* d_in, const int* in_sizes, int n_in,
                              void* d_out, int out_size, void* d_ws, size_t ws_size,
                              hipStream_t stream) {
  const float* x    = (const float*)d_in[0];
  const float* c1w  = (const float*)d_in[1];
  const float* c1b  = (const float*)d_in[2];
  const float* c2w  = (const float*)d_in[3];
  const float* c2b  = (const float*)d_in[4];
  const float* lnfg = (const float*)d_in[5];
  const float* lnfb = (const float*)d_in[6];
  const float* tw   = (const float*)d_in[7];
  const float* tb   = (const float*)d_in[8];
  const float* sw   = (const float*)d_in[9];
  const float* sb   = (const float*)d_in[10];
  const float* aiw  = (const float*)d_in[11];
  const float* aib  = (const float*)d_in[12];
  const float* aow  = (const float*)d_in[13];
  const float* aobb = (const float*)d_in[14];
  const float* l1g  = (const float*)d_in[15];
  const float* l1b  = (const float*)d_in[16];
  const float* f1w  = (const float*)d_in[17];
  const float* f1b  = (const float*)d_in[18];
  const float* f2w  = (const float*)d_in[19];
  const float* f2b  = (const float*)d_in[20];
  const float* l2g  = (const float*)d_in[21];
  const float* l2b  = (const float*)d_in[22];
  const float* fcw  = (const float*)d_in[23];
  const float* fcb  = (const float*)d_in[24];
  float* out = (float*)d_out;
  ushort* ws = (ushort*)d_ws;

  k_cvt<<<4096, NTH, 0, stream>>>(c2w, tw, sw, aiw, aow, f1w, f2w, ws);
  aai_main<<<32, NTH, 0, stream>>>(x, c1w, c1b, c2b, lnfg, lnfb, tb, sb, aib,
                                   aobb, l1g, l1b, f1b, f2b, l2g, l2b, fcw,
                                   fcb, ws, out);
}

// Round 5
// 378.529 us; speedup vs baseline: 4.3685x; 1.1371x over previous
//
#include <hip/hip_runtime.h>
#include <math.h>

#define NTH 1024

typedef __attribute__((ext_vector_type(8))) short short8;
typedef __attribute__((ext_vector_type(4))) float f32x4;
typedef unsigned short ushort;
typedef unsigned int uint;

#define MFMA16(a, b, c) __builtin_amdgcn_mfma_f32_16x16x32_bf16(a, b, c, 0, 0, 0)

// fp32 -> bf16 round-to-nearest-even
__device__ __forceinline__ ushort f2bf(float f) {
  uint u = __float_as_uint(f);
  u = (u + 0x7FFFu + ((u >> 16) & 1u)) >> 16;
  return (ushort)u;
}

// Flat-index LDS XOR-swizzle (T2): permutes 16B slots within a 128B window.
// Write and read must use the same (idx, sh). sh = log2(row stride in ushorts)
// for pow2 strides; sh=8 also works for stride 768 (3 coprime 8).
__device__ __forceinline__ int swz(int idx, int sh) {
  return idx ^ (((idx >> sh) & 7) << 3);
}

__device__ __forceinline__ float wsum(float v) {
#pragma unroll
  for (int off = 32; off > 0; off >>= 1) v += __shfl_xor(v, off, 64);
  return v;
}

// ---- weight convert kernel: fp32 inputs -> bf16 in d_ws ------------------
#define W2R 0            // [256][768]  conv2 re-layout: w2r[o][t*256+e] = c2w[o][e*3+t]
#define TWO 196608       // [256][256]
#define SWO 262144       // [256][256]
#define QKVO 327680      // [4][768][256]
#define AOWO 1114112     // [4][256][256]
#define F1O 1376256      // [4][1024][256]
#define F2O 2424832      // [4][256][1024]
#define WTOT 3473408

__global__ void k_cvt(const float* __restrict__ c2w, const float* __restrict__ tw,
                      const float* __restrict__ sw, const float* __restrict__ aiw,
                      const float* __restrict__ aow, const float* __restrict__ f1w,
                      const float* __restrict__ f2w, ushort* __restrict__ ws) {
  for (int i = blockIdx.x * blockDim.x + threadIdx.x; i < WTOT;
       i += gridDim.x * blockDim.x) {
    float v;
    if (i < TWO) {
      int o = i / 768, k = i - o * 768;
      int t = k >> 8, e = k & 255;
      v = c2w[o * 768 + e * 3 + t];
    } else if (i < SWO) v = tw[i - TWO];
    else if (i < QKVO) v = sw[i - SWO];
    else if (i < AOWO) v = aiw[i - QKVO];
    else if (i < F1O)  v = aow[i - AOWO];
    else if (i < F2O)  v = f1w[i - F1O];
    else               v = f2w[i - F2O];
    ws[i] = f2bf(v);
  }
}

// ---- MFMA GEMM: out[20][...] = act(bias + A[20][K] * W[N][K]^T) ----------
// 16 waves, each handling column tiles tile0 + wv + 16*i (i < NTILES/16).
#define M_F32 0
#define M_F32RELU 1
#define M_SINADD 2
#define M_BF16 3
#define M_BF16RELU 4
#define M_QKV 5

template <int KDIM, int NTILES, int MODE, int ASH, int OSH>
__device__ __forceinline__ void gemm20(const ushort* __restrict__ A, int lda,
                                       const ushort* __restrict__ Wg,
                                       const float* __restrict__ bias,
                                       float* __restrict__ outf,
                                       ushort* __restrict__ outb, int ostride,
                                       ushort* __restrict__ vt, int tid,
                                       int tile0) {
  constexpr int NCH = KDIM / 128;
  constexpr int MY = NTILES / 16;
  const int lane = tid & 63;
  const int wv = tid >> 6;  // 0..15
  const int col = lane & 15;
  const int kg = lane >> 4;
  const int r0 = col;
  const int r1c = (16 + col > 19) ? 19 : (16 + col);

  f32x4 acc[MY][2];
#pragma unroll
  for (int i = 0; i < MY; ++i) {
    const float bv = bias[(tile0 + wv + 16 * i) * 16 + col];
#pragma unroll
    for (int mt = 0; mt < 2; ++mt) acc[i][mt] = {bv, bv, bv, bv};
  }

#pragma unroll 2
  for (int kc = 0; kc < NCH; ++kc) {
    short8 af[2][4];
#pragma unroll
    for (int ks = 0; ks < 4; ++ks) {
      const int k0 = kc * 128 + ks * 32 + kg * 8;
      af[0][ks] = *(const short8*)(A + swz(r0 * lda + k0, ASH));
      af[1][ks] = *(const short8*)(A + swz(r1c * lda + k0, ASH));
    }
#pragma unroll
    for (int i = 0; i < MY; ++i) {
      const ushort* wb =
          Wg + (size_t)((tile0 + wv + 16 * i) * 16 + col) * KDIM + kc * 128 +
          kg * 8;
#pragma unroll
      for (int ks = 0; ks < 4; ++ks) {
        short8 bf = *(const short8*)(wb + ks * 32);
        acc[i][0] = MFMA16(af[0][ks], bf, acc[i][0]);
        acc[i][1] = MFMA16(af[1][ks], bf, acc[i][1]);
      }
    }
  }

#pragma unroll
  for (int i = 0; i < MY; ++i) {
    const int og = (tile0 + wv + 16 * i) * 16 + col;
#pragma unroll
    for (int mt = 0; mt < 2; ++mt) {
#pragma unroll
      for (int j = 0; j < 4; ++j) {
        const int row = mt * 16 + kg * 4 + j;
        if (row < 20) {
          float v = acc[i][mt][j];
          if (MODE == M_F32) outf[row * ostride + og] = v;
          if (MODE == M_F32RELU) outf[row * ostride + og] = fmaxf(v, 0.f);
          if (MODE == M_SINADD) outf[row * ostride + og] += sinf(v);
          if (MODE == M_BF16) outb[swz(row * ostride + og, OSH)] = f2bf(v);
          if (MODE == M_BF16RELU)
            outb[swz(row * ostride + og, OSH)] = f2bf(fmaxf(v, 0.f));
          if (MODE == M_QKV) {
            ushort bv = f2bf(v);
            outb[swz(row * ostride + og, OSH)] = bv;
            if (og >= 512) {  // V part -> transposed copy vt[h][dh][token]
              int hh = (og - 512) >> 5, dh = (og - 512) & 31;
              vt[swz(hh * 1024 + dh * 32 + row, 5)] = bv;
            }
          }
        }
      }
    }
  }
}

// in-place LayerNorm over 20 rows of H; optional residual add; bf16 mirror hb
__device__ __forceinline__ void ln20(float (*H)[256], ushort* __restrict__ hb,
                                     const float* __restrict__ add,
                                     const float* __restrict__ g,
                                     const float* __restrict__ bt, int tid) {
  const int lane = tid & 63;
  const int wv = tid >> 6;
  const int d0 = lane * 4;
  for (int r = wv; r < 20; r += 16) {
    float xv[4];
#pragma unroll
    for (int j = 0; j < 4; ++j) {
      xv[j] = H[r][d0 + j];
      if (add) xv[j] += add[r * 256 + d0 + j];
    }
    float m = wsum(xv[0] + xv[1] + xv[2] + xv[3]) * (1.f / 256.f);
    float c0 = xv[0] - m, c1 = xv[1] - m, c2 = xv[2] - m, c3 = xv[3] - m;
    float var = wsum(c0 * c0 + c1 * c1 + c2 * c2 + c3 * c3) * (1.f / 256.f);
    float inv = rsqrtf(var + 1e-5f);
#pragma unroll
    for (int j = 0; j < 4; ++j) {
      float cj = (j == 0 ? c0 : j == 1 ? c1 : j == 2 ? c2 : c3);
      float o = cj * inv * g[d0 + j] + bt[d0 + j];
      H[r][d0 + j] = o;
      hb[swz(r * 256 + d0 + j, 8)] = f2bf(o);
    }
  }
}

__global__ __launch_bounds__(NTH) void aai_main(
    const float* __restrict__ x, const float* __restrict__ c1w,
    const float* __restrict__ c1b, const float* __restrict__ c2b,
    const float* __restrict__ lnfg, const float* __restrict__ lnfb,
    const float* __restrict__ tb, const float* __restrict__ sb,
    const float* __restrict__ aib, const float* __restrict__ aob_b,
    const float* __restrict__ l1g, const float* __restrict__ l1b,
    const float* __restrict__ f1b, const float* __restrict__ f2b,
    const float* __restrict__ l2g, const float* __restrict__ l2b,
    const float* __restrict__ fcw, const float* __restrict__ fcb,
    const ushort* __restrict__ ws, float* __restrict__ out) {
  __shared__ float xs[24][16];
  __shared__ float h[20][256];
  __shared__ float bb[20][256];
  __shared__ __align__(16) ushort hb[20 * 256];
  __shared__ __align__(16) ushort qkvb[20 * 768];
  __shared__ __align__(16) ushort big[20480];  // c1[22][256] | {aob,P,vT} | ffb[20][1024]
  __shared__ float scores[8 * 20 * 20];

  const int tid = threadIdx.x;
  const int b = blockIdx.x;
  const int lane = tid & 63;
  const int wv = tid >> 6;
  const int col = lane & 15;
  const int kg = lane >> 4;
  const int r1c = (16 + col > 19) ? 19 : (16 + col);

  ushort* c1u = big;           // [22][256]  (swz sh=8)
  ushort* ffb = big;           // [20][1024] (swz sh=10)
  ushort* aob = big;           // [20][256]  (swz sh=8)
  ushort* Pb = big + 5120;     // [8][20][32] (swz sh=5)
  ushort* vT = big + 10240;    // [8][32][32] (swz sh=5)

  // ---- stage x tail (t = 3977..3999, row 23 = 0)
  for (int i = tid; i < 24 * 16; i += NTH) {
    int r = i >> 4, c = i & 15;
    xs[r][c] = (r < 23) ? x[((size_t)b * 4000 + 3977 + r) * 16 + c] : 0.f;
  }
  __syncthreads();

  // ---- conv1 + ReLU -> c1 bf16 (rows t=3979..3999, row 21 = t=4000 = 0)
  if (tid < 256) {
    const int d = tid;
    const float* wr = c1w + d * 48;
    float acc[21];
    const float bv = c1b[d];
#pragma unroll
    for (int r = 0; r < 21; ++r) acc[r] = bv;
    for (int c = 0; c < 16; ++c) {
      float xv[23];
#pragma unroll
      for (int i = 0; i < 23; ++i) xv[i] = xs[i + 1][c];
      float w0 = wr[c * 3], w1 = wr[c * 3 + 1], w2 = wr[c * 3 + 2];
#pragma unroll
      for (int r = 0; r < 21; ++r)
        acc[r] += xv[r] * w0 + xv[r + 1] * w1 + xv[r + 2] * w2;
    }
#pragma unroll
    for (int r = 0; r < 21; ++r)
      c1u[swz(r * 256 + d, 8)] = f2bf(fmaxf(acc[r], 0.f));
    c1u[swz(21 * 256 + d, 8)] = 0;
  }
  __syncthreads();

  // ---- conv2 + ReLU -> h fp32 (GEMM: A[r][k]=c1_flat[r*256+k], K=768)
  gemm20<768, 16, M_F32RELU, 8, 8>(c1u, 256, ws + W2R, c2b, &h[0][0], nullptr,
                                   256, nullptr, tid, 0);
  __syncthreads();

  // ---- LayerNorm_f
  ln20(h, hb, nullptr, lnfg, lnfb, tid);
  __syncthreads();

  // ---- trend -> bb ; season -> bb += sin(.)
  gemm20<256, 16, M_F32, 8, 8>(hb, 256, ws + TWO, tb, &bb[0][0], nullptr, 256,
                               nullptr, tid, 0);
  __syncthreads();
  gemm20<256, 16, M_SINADD, 8, 8>(hb, 256, ws + SWO, sb, &bb[0][0], nullptr,
                                  256, nullptr, tid, 0);
  __syncthreads();
  for (int i = tid; i < 20 * 256; i += NTH) {
    float v = (&h[0][0])[i] + (&bb[0][0])[i];
    (&h[0][0])[i] = v;
    hb[swz(i, 8)] = f2bf(v);
  }
  __syncthreads();

  // ---- encoder layers
  for (int l = 0; l < 4; ++l) {
    // qkv projection: Q,K tiles 0..31; V tiles 32..47 (+ transposed vT).
    gemm20<256, 32, M_BF16, 8, 8>(hb, 256, ws + QKVO + l * 196608,
                                  aib + l * 768, nullptr, qkvb, 768, nullptr,
                                  tid, 0);
    gemm20<256, 16, M_QKV, 8, 8>(hb, 256, ws + QKVO + l * 196608,
                                 aib + l * 768, nullptr, qkvb, 768, vT, tid,
                                 32);
    // vT pad tokens 20..31 never written by the epilogue -> zero (layer-0 LDS
    // garbage there can be NaN/Inf bf16 and 0*Inf = NaN in the PV MFMA).
    for (int i = tid; i < 8 * 32 * 12; i += NTH) {
      int hh = i / 384, r = i - hh * 384;
      int dh = r / 12, tk = 20 + (r - dh * 12);
      vT[swz(hh * 1024 + dh * 32 + tk, 5)] = 0;
    }
    __syncthreads();

    // scores = Q.K^T / sqrt(32), one head per wave (wv<8), MFMA K=32
    if (wv < 8) {
      const int hh = wv;
      short8 aq[2], bk[2];
      aq[0] = *(const short8*)(qkvb + swz(col * 768 + hh * 32 + kg * 8, 8));
      aq[1] = *(const short8*)(qkvb + swz(r1c * 768 + hh * 32 + kg * 8, 8));
      bk[0] = *(const short8*)(qkvb + swz(col * 768 + 256 + hh * 32 + kg * 8, 8));
      bk[1] = *(const short8*)(qkvb + swz(r1c * 768 + 256 + hh * 32 + kg * 8, 8));
      f32x4 dqk[2][2];
#pragma unroll
      for (int mt = 0; mt < 2; ++mt)
#pragma unroll
        for (int nt = 0; nt < 2; ++nt) {
          dqk[mt][nt] = {0.f, 0.f, 0.f, 0.f};
          dqk[mt][nt] = MFMA16(aq[mt], bk[nt], dqk[mt][nt]);
        }
#pragma unroll
      for (int mt = 0; mt < 2; ++mt)
#pragma unroll
        for (int nt = 0; nt < 2; ++nt)
#pragma unroll
          for (int j = 0; j < 4; ++j) {
            int row = mt * 16 + kg * 4 + j, kj = nt * 16 + col;
            if (row < 20 && kj < 20)
              scores[hh * 400 + row * 20 + kj] =
                  dqk[mt][nt][j] * 0.17677669529663687f;
          }
    }
    __syncthreads();

    // softmax rows -> P bf16 [8][20][32], zero-padded to K=32
    if (tid < 160) {
      const int hh = tid / 20, q = tid - hh * 20;
      const float* row = scores + hh * 400 + q * 20;
      float m = row[0];
#pragma unroll
      for (int j = 1; j < 20; ++j) m = fmaxf(m, row[j]);
      float e[20], s = 0.f;
#pragma unroll
      for (int j = 0; j < 20; ++j) { e[j] = __expf(row[j] - m); s += e[j]; }
      float inv = 1.f / s;
#pragma unroll
      for (int j = 0; j < 20; ++j)
        Pb[swz(hh * 640 + q * 32 + j, 5)] = f2bf(e[j] * inv);
#pragma unroll
      for (int j = 20; j < 32; ++j) Pb[swz(hh * 640 + q * 32 + j, 5)] = 0;
    }
    __syncthreads();

    // O = P @ V per head (wv<8) via MFMA (K=32) -> aob bf16
    if (wv < 8) {
      const int hh = wv;
      short8 ap[2], bv[2];
      ap[0] = *(const short8*)(Pb + swz(hh * 640 + col * 32 + kg * 8, 5));
      ap[1] = *(const short8*)(Pb + swz(hh * 640 + r1c * 32 + kg * 8, 5));
      bv[0] = *(const short8*)(vT + swz(hh * 1024 + col * 32 + kg * 8, 5));
      bv[1] = *(const short8*)(vT + swz(hh * 1024 + (16 + col) * 32 + kg * 8, 5));
      f32x4 dav[2][2];
#pragma unroll
      for (int mt = 0; mt < 2; ++mt)
#pragma unroll
        for (int nt = 0; nt < 2; ++nt) {
          dav[mt][nt] = {0.f, 0.f, 0.f, 0.f};
          dav[mt][nt] = MFMA16(ap[mt], bv[nt], dav[mt][nt]);
        }
#pragma unroll
      for (int mt = 0; mt < 2; ++mt)
#pragma unroll
        for (int nt = 0; nt < 2; ++nt)
#pragma unroll
          for (int j = 0; j < 4; ++j) {
            int row = mt * 16 + kg * 4 + j, dc = nt * 16 + col;
            if (row < 20)
              aob[swz(row * 256 + hh * 32 + dc, 8)] = f2bf(dav[mt][nt][j]);
          }
    }
    __syncthreads();

    // out projection -> bb fp32
    gemm20<256, 16, M_F32, 8, 8>(aob, 256, ws + AOWO + l * 65536,
                                 aob_b + l * 256, &bb[0][0], nullptr, 256,
                                 nullptr, tid, 0);
    __syncthreads();
    // h = LN1(h + proj)
    ln20(h, hb, &bb[0][0], l1g + l * 256, l1b + l * 256, tid);
    __syncthreads();
    // ff1 + ReLU -> ffb bf16 [20][1024] (two halves)
    gemm20<256, 32, M_BF16RELU, 8, 10>(hb, 256, ws + F1O + l * 262144,
                                       f1b + l * 1024, nullptr, ffb, 1024,
                                       nullptr, tid, 0);
    gemm20<256, 32, M_BF16RELU, 8, 10>(hb, 256, ws + F1O + l * 262144,
                                       f1b + l * 1024, nullptr, ffb, 1024,
                                       nullptr, tid, 32);
    __syncthreads();
    // ff2 -> bb fp32
    gemm20<1024, 16, M_F32, 10, 8>(ffb, 1024, ws + F2O + l * 262144,
                                   f2b + l * 256, &bb[0][0], nullptr, 256,
                                   nullptr, tid, 0);
    __syncthreads();
    // h = LN2(h + ff)
    ln20(h, hb, &bb[0][0], l2g + l * 256, l2b + l * 256, tid);
    __syncthreads();
  }

  // ---- final fc on last token (row 19), fp32: one wave per output
  if (wv < 16) {
    float4 hv = *(const float4*)(&h[19][lane * 4]);
    float4 w4 = *(const float4*)(&fcw[wv * 256 + lane * 4]);
    float s = hv.x * w4.x + hv.y * w4.y + hv.z * w4.z + hv.w * w4.w;
    s = wsum(s);
    if (lane == 0) out[b * 16 + wv] = s + fcb[wv];
  }
}

extern "C" void kernel_launch(void* const* d_in, const int* in_sizes, int n_in,
                              void* d_out, int out_size, void* d_ws, size_t ws_size,
                              hipStream_t stream) {
  const float* x    = (const float*)d_in[0];
  const float* c1w  = (const float*)d_in[1];
  const float* c1b  = (const float*)d_in[2];
  const float* c2w  = (const float*)d_in[3];
  const float* c2b  = (const float*)d_in[4];
  const float* lnfg = (const float*)d_in[5];
  const float* lnfb = (const float*)d_in[6];
  const float* tw   = (const float*)d_in[7];
  const float* tb   = (const float*)d_in[8];
  const float* sw   = (const float*)d_in[9];
  const float* sb   = (const float*)d_in[10];
  const float* aiw  = (const float*)d_in[11];
  const float* aib  = (const float*)d_in[12];
  const float* aow  = (const float*)d_in[13];
  const float* aobb = (const float*)d_in[14];
  const float* l1g  = (const float*)d_in[15];
  const float* l1b  = (const float*)d_in[16];
  const float* f1w  = (const float*)d_in[17];
  const float* f1b  = (const float*)d_in[18];
  const float* f2w  = (const float*)d_in[19];
  const float* f2b  = (const float*)d_in[20];
  const float* l2g  = (const float*)d_in[21];
  const float* l2b  = (const float*)d_in[22];
  const float* fcw  = (const float*)d_in[23];
  const float* fcb  = (const float*)d_in[24];
  float* out = (float*)d_out;
  ushort* ws = (ushort*)d_ws;

  k_cvt<<<4096, 256, 0, stream>>>(c2w, tw, sw, aiw, aow, f1w, f2w, ws);
  aai_main<<<32, NTH, 0, stream>>>(x, c1w, c1b, c2b, lnfg, lnfb, tb, sb, aib,
                                   aobb, l1g, l1b, f1b, f2b, l2g, l2b, fcw,
                                   fcb, ws, out);
}

// Round 6
// 376.267 us; speedup vs baseline: 4.3948x; 1.0060x over previous
//
#include <hip/hip_runtime.h>
#include <math.h>

#define NTH 1024

typedef __attribute__((ext_vector_type(8))) short short8;
typedef __attribute__((ext_vector_type(4))) float f32x4;
typedef unsigned short ushort;
typedef unsigned int uint;

#define MFMA16(a, b, c) __builtin_amdgcn_mfma_f32_16x16x32_bf16(a, b, c, 0, 0, 0)

// fp32 -> bf16 round-to-nearest-even
__device__ __forceinline__ ushort f2bf(float f) {
  uint u = __float_as_uint(f);
  u = (u + 0x7FFFu + ((u >> 16) & 1u)) >> 16;
  return (ushort)u;
}

// Flat-index LDS XOR-swizzle (T2): permutes 16B slots within a 128B window.
// Write and read must use the same (idx, sh).
__device__ __forceinline__ int swz(int idx, int sh) {
  return idx ^ (((idx >> sh) & 7) << 3);
}

__device__ __forceinline__ float wsum(float v) {
#pragma unroll
  for (int off = 32; off > 0; off >>= 1) v += __shfl_xor(v, off, 64);
  return v;
}

// ---- weight convert kernel: fp32 inputs -> bf16 in d_ws ------------------
#define W2R 0            // [256][768]  conv2 re-layout: w2r[o][t*256+e] = c2w[o][e*3+t]
#define TWO 196608       // [256][256]
#define SWO 262144       // [256][256]
#define QKVO 327680      // [4][768][256]
#define AOWO 1114112     // [4][256][256]
#define F1O 1376256      // [4][1024][256]
#define F2O 2424832      // [4][256][1024]
#define WTOT 3473408

__global__ void k_cvt(const float* __restrict__ c2w, const float* __restrict__ tw,
                      const float* __restrict__ sw, const float* __restrict__ aiw,
                      const float* __restrict__ aow, const float* __restrict__ f1w,
                      const float* __restrict__ f2w, ushort* __restrict__ ws) {
  for (int i = blockIdx.x * blockDim.x + threadIdx.x; i < WTOT;
       i += gridDim.x * blockDim.x) {
    float v;
    if (i < TWO) {
      int o = i / 768, k = i - o * 768;
      int t = k >> 8, e = k & 255;
      v = c2w[o * 768 + e * 3 + t];
    } else if (i < SWO) v = tw[i - TWO];
    else if (i < QKVO) v = sw[i - SWO];
    else if (i < AOWO) v = aiw[i - QKVO];
    else if (i < F1O)  v = aow[i - AOWO];
    else if (i < F2O)  v = f1w[i - F1O];
    else               v = f2w[i - F2O];
    ws[i] = f2bf(v);
  }
}

// ---- MFMA GEMM: out[20][...] = act(bias + A[20][K] * W[N][K]^T) ----------
// 16 waves, each handling column tiles tile0 + wv + 16*i (i < NTILES/16).
#define M_F32 0
#define M_F32RELU 1
#define M_SINADD 2
#define M_BF16 3
#define M_BF16RELU 4
#define M_QKV 5

template <int KDIM, int NTILES, int MODE, int ASH, int OSH>
__device__ __forceinline__ void gemm20(const ushort* __restrict__ A, int lda,
                                       const ushort* __restrict__ Wg,
                                       const float* __restrict__ bias,
                                       float* __restrict__ outf,
                                       ushort* __restrict__ outb, int ostride,
                                       ushort* __restrict__ vt, int tid,
                                       int tile0) {
  constexpr int NCH = KDIM / 128;
  constexpr int MY = NTILES / 16;
  const int lane = tid & 63;
  const int wv = tid >> 6;  // 0..15
  const int col = lane & 15;
  const int kg = lane >> 4;
  const int r0 = col;
  const int r1c = (16 + col > 19) ? 19 : (16 + col);

  f32x4 acc[MY][2];
#pragma unroll
  for (int i = 0; i < MY; ++i) {
    const float bv = bias[(tile0 + wv + 16 * i) * 16 + col];
#pragma unroll
    for (int mt = 0; mt < 2; ++mt) acc[i][mt] = {bv, bv, bv, bv};
  }

#pragma unroll 2
  for (int kc = 0; kc < NCH; ++kc) {
    short8 af[2][4];
#pragma unroll
    for (int ks = 0; ks < 4; ++ks) {
      const int k0 = kc * 128 + ks * 32 + kg * 8;
      af[0][ks] = *(const short8*)(A + swz(r0 * lda + k0, ASH));
      af[1][ks] = *(const short8*)(A + swz(r1c * lda + k0, ASH));
    }
#pragma unroll
    for (int i = 0; i < MY; ++i) {
      const ushort* wb =
          Wg + (size_t)((tile0 + wv + 16 * i) * 16 + col) * KDIM + kc * 128 +
          kg * 8;
#pragma unroll
      for (int ks = 0; ks < 4; ++ks) {
        short8 bf = *(const short8*)(wb + ks * 32);
        acc[i][0] = MFMA16(af[0][ks], bf, acc[i][0]);
        acc[i][1] = MFMA16(af[1][ks], bf, acc[i][1]);
      }
    }
  }

#pragma unroll
  for (int i = 0; i < MY; ++i) {
    const int og = (tile0 + wv + 16 * i) * 16 + col;
#pragma unroll
    for (int mt = 0; mt < 2; ++mt) {
#pragma unroll
      for (int j = 0; j < 4; ++j) {
        const int row = mt * 16 + kg * 4 + j;
        if (row < 20) {
          float v = acc[i][mt][j];
          if (MODE == M_F32) outf[row * ostride + og] = v;
          if (MODE == M_F32RELU) outf[row * ostride + og] = fmaxf(v, 0.f);
          if (MODE == M_SINADD) outf[row * ostride + og] += sinf(v);
          if (MODE == M_BF16) outb[swz(row * ostride + og, OSH)] = f2bf(v);
          if (MODE == M_BF16RELU)
            outb[swz(row * ostride + og, OSH)] = f2bf(fmaxf(v, 0.f));
          if (MODE == M_QKV) {
            ushort bv = f2bf(v);
            outb[swz(row * ostride + og, OSH)] = bv;
            if (og >= 512) {  // V part -> transposed copy vt[h][dh][token]
              int hh = (og - 512) >> 5, dh = (og - 512) & 31;
              vt[swz(hh * 1024 + dh * 32 + row, 5)] = bv;
            }
          }
        }
      }
    }
  }
}

// in-place LayerNorm over 20 rows of H; optional residual add; bf16 mirror hb
__device__ __forceinline__ void ln20(float (*H)[256], ushort* __restrict__ hb,
                                     const float* __restrict__ add,
                                     const float* __restrict__ g,
                                     const float* __restrict__ bt, int tid) {
  const int lane = tid & 63;
  const int wv = tid >> 6;
  const int d0 = lane * 4;
  for (int r = wv; r < 20; r += 16) {
    float xv[4];
#pragma unroll
    for (int j = 0; j < 4; ++j) {
      xv[j] = H[r][d0 + j];
      if (add) xv[j] += add[r * 256 + d0 + j];
    }
    float m = wsum(xv[0] + xv[1] + xv[2] + xv[3]) * (1.f / 256.f);
    float c0 = xv[0] - m, c1 = xv[1] - m, c2 = xv[2] - m, c3 = xv[3] - m;
    float var = wsum(c0 * c0 + c1 * c1 + c2 * c2 + c3 * c3) * (1.f / 256.f);
    float inv = rsqrtf(var + 1e-5f);
#pragma unroll
    for (int j = 0; j < 4; ++j) {
      float cj = (j == 0 ? c0 : j == 1 ? c1 : j == 2 ? c2 : c3);
      float o = cj * inv * g[d0 + j] + bt[d0 + j];
      H[r][d0 + j] = o;
      hb[swz(r * 256 + d0 + j, 8)] = f2bf(o);
    }
  }
}

// launch_bounds(1024, 4): min 4 waves/EU = one 16-wave block resident/CU ->
// VGPR cap 128 (not 64). R5's (1024) default targeted 2 blocks/CU -> 64 VGPRs
// -> 26 MB of scratch spill traffic (WRITE_SIZE counter).
__global__ __launch_bounds__(NTH, 4) void aai_main(
    const float* __restrict__ x, const float* __restrict__ c1w,
    const float* __restrict__ c1b, const float* __restrict__ c2b,
    const float* __restrict__ lnfg, const float* __restrict__ lnfb,
    const float* __restrict__ tb, const float* __restrict__ sb,
    const float* __restrict__ aib, const float* __restrict__ aob_b,
    const float* __restrict__ l1g, const float* __restrict__ l1b,
    const float* __restrict__ f1b, const float* __restrict__ f2b,
    const float* __restrict__ l2g, const float* __restrict__ l2b,
    const float* __restrict__ fcw, const float* __restrict__ fcb,
    const ushort* __restrict__ ws, float* __restrict__ out) {
  __shared__ float xs[24][16];
  __shared__ float h[20][256];
  __shared__ float bb[20][256];
  __shared__ __align__(16) ushort hb[20 * 256];
  __shared__ __align__(16) ushort qkvb[20 * 768];
  __shared__ __align__(16) ushort big[20480];  // c1[22][256] | {aob,P,vT} | ffb[20][1024]
  __shared__ float scores[8 * 20 * 20];

  const int tid = threadIdx.x;
  const int b = blockIdx.x;
  const int lane = tid & 63;
  const int wv = tid >> 6;
  const int col = lane & 15;
  const int kg = lane >> 4;
  const int r1c = (16 + col > 19) ? 19 : (16 + col);

  ushort* c1u = big;           // [22][256]  (swz sh=8)
  ushort* ffb = big;           // [20][1024] (swz sh=10)
  ushort* aob = big;           // [20][256]  (swz sh=8)
  ushort* Pb = big + 5120;     // [8][20][32] (swz sh=5)
  ushort* vT = big + 10240;    // [8][32][32] (swz sh=5)

  // ---- stage x tail (t = 3977..3999, row 23 = 0)
  for (int i = tid; i < 24 * 16; i += NTH) {
    int r = i >> 4, c = i & 15;
    xs[r][c] = (r < 23) ? x[((size_t)b * 4000 + 3977 + r) * 16 + c] : 0.f;
  }
  __syncthreads();

  // ---- conv1 + ReLU -> c1 bf16 (rows t=3979..3999, row 21 = t=4000 = 0)
  if (tid < 256) {
    const int d = tid;
    const float* wr = c1w + d * 48;
    float acc[21];
    const float bv = c1b[d];
#pragma unroll
    for (int r = 0; r < 21; ++r) acc[r] = bv;
    for (int c = 0; c < 16; ++c) {
      float xv[23];
#pragma unroll
      for (int i = 0; i < 23; ++i) xv[i] = xs[i + 1][c];
      float w0 = wr[c * 3], w1 = wr[c * 3 + 1], w2 = wr[c * 3 + 2];
#pragma unroll
      for (int r = 0; r < 21; ++r)
        acc[r] += xv[r] * w0 + xv[r + 1] * w1 + xv[r + 2] * w2;
    }
#pragma unroll
    for (int r = 0; r < 21; ++r)
      c1u[swz(r * 256 + d, 8)] = f2bf(fmaxf(acc[r], 0.f));
    c1u[swz(21 * 256 + d, 8)] = 0;
  }
  __syncthreads();

  // ---- conv2 + ReLU -> h fp32 (GEMM: A[r][k]=c1_flat[r*256+k], K=768)
  gemm20<768, 16, M_F32RELU, 8, 8>(c1u, 256, ws + W2R, c2b, &h[0][0], nullptr,
                                   256, nullptr, tid, 0);
  __syncthreads();

  // ---- LayerNorm_f
  ln20(h, hb, nullptr, lnfg, lnfb, tid);
  __syncthreads();

  // ---- trend -> bb ; season -> bb += sin(.)
  gemm20<256, 16, M_F32, 8, 8>(hb, 256, ws + TWO, tb, &bb[0][0], nullptr, 256,
                               nullptr, tid, 0);
  __syncthreads();
  gemm20<256, 16, M_SINADD, 8, 8>(hb, 256, ws + SWO, sb, &bb[0][0], nullptr,
                                  256, nullptr, tid, 0);
  __syncthreads();
  for (int i = tid; i < 20 * 256; i += NTH) {
    float v = (&h[0][0])[i] + (&bb[0][0])[i];
    (&h[0][0])[i] = v;
    hb[swz(i, 8)] = f2bf(v);
  }
  __syncthreads();

  // ---- encoder layers
  for (int l = 0; l < 4; ++l) {
    // qkv projection: Q,K tiles 0..31; V tiles 32..47 (+ transposed vT).
    gemm20<256, 32, M_BF16, 8, 8>(hb, 256, ws + QKVO + l * 196608,
                                  aib + l * 768, nullptr, qkvb, 768, nullptr,
                                  tid, 0);
    gemm20<256, 16, M_QKV, 8, 8>(hb, 256, ws + QKVO + l * 196608,
                                 aib + l * 768, nullptr, qkvb, 768, vT, tid,
                                 32);
    // vT pad tokens 20..31 never written by the epilogue -> zero (layer-0 LDS
    // garbage there can be NaN/Inf bf16 and 0*Inf = NaN in the PV MFMA).
    for (int i = tid; i < 8 * 32 * 12; i += NTH) {
      int hh = i / 384, r = i - hh * 384;
      int dh = r / 12, tk = 20 + (r - dh * 12);
      vT[swz(hh * 1024 + dh * 32 + tk, 5)] = 0;
    }
    __syncthreads();

    // scores = Q.K^T / sqrt(32), one head per wave (wv<8), MFMA K=32
    if (wv < 8) {
      const int hh = wv;
      short8 aq[2], bk[2];
      aq[0] = *(const short8*)(qkvb + swz(col * 768 + hh * 32 + kg * 8, 8));
      aq[1] = *(const short8*)(qkvb + swz(r1c * 768 + hh * 32 + kg * 8, 8));
      bk[0] = *(const short8*)(qkvb + swz(col * 768 + 256 + hh * 32 + kg * 8, 8));
      bk[1] = *(const short8*)(qkvb + swz(r1c * 768 + 256 + hh * 32 + kg * 8, 8));
      f32x4 dqk[2][2];
#pragma unroll
      for (int mt = 0; mt < 2; ++mt)
#pragma unroll
        for (int nt = 0; nt < 2; ++nt) {
          dqk[mt][nt] = {0.f, 0.f, 0.f, 0.f};
          dqk[mt][nt] = MFMA16(aq[mt], bk[nt], dqk[mt][nt]);
        }
#pragma unroll
      for (int mt = 0; mt < 2; ++mt)
#pragma unroll
        for (int nt = 0; nt < 2; ++nt)
#pragma unroll
          for (int j = 0; j < 4; ++j) {
            int row = mt * 16 + kg * 4 + j, kj = nt * 16 + col;
            if (row < 20 && kj < 20)
              scores[hh * 400 + row * 20 + kj] =
                  dqk[mt][nt][j] * 0.17677669529663687f;
          }
    }
    __syncthreads();

    // softmax rows -> P bf16 [8][20][32], zero-padded to K=32
    if (tid < 160) {
      const int hh = tid / 20, q = tid - hh * 20;
      const float* row = scores + hh * 400 + q * 20;
      float m = row[0];
#pragma unroll
      for (int j = 1; j < 20; ++j) m = fmaxf(m, row[j]);
      float e[20], s = 0.f;
#pragma unroll
      for (int j = 0; j < 20; ++j) { e[j] = __expf(row[j] - m); s += e[j]; }
      float inv = 1.f / s;
#pragma unroll
      for (int j = 0; j < 20; ++j)
        Pb[swz(hh * 640 + q * 32 + j, 5)] = f2bf(e[j] * inv);
#pragma unroll
      for (int j = 20; j < 32; ++j) Pb[swz(hh * 640 + q * 32 + j, 5)] = 0;
    }
    __syncthreads();

    // O = P @ V per head (wv<8) via MFMA (K=32) -> aob bf16
    if (wv < 8) {
      const int hh = wv;
      short8 ap[2], bv[2];
      ap[0] = *(const short8*)(Pb + swz(hh * 640 + col * 32 + kg * 8, 5));
      ap[1] = *(const short8*)(Pb + swz(hh * 640 + r1c * 32 + kg * 8, 5));
      bv[0] = *(const short8*)(vT + swz(hh * 1024 + col * 32 + kg * 8, 5));
      bv[1] = *(const short8*)(vT + swz(hh * 1024 + (16 + col) * 32 + kg * 8, 5));
      f32x4 dav[2][2];
#pragma unroll
      for (int mt = 0; mt < 2; ++mt)
#pragma unroll
        for (int nt = 0; nt < 2; ++nt) {
          dav[mt][nt] = {0.f, 0.f, 0.f, 0.f};
          dav[mt][nt] = MFMA16(ap[mt], bv[nt], dav[mt][nt]);
        }
#pragma unroll
      for (int mt = 0; mt < 2; ++mt)
#pragma unroll
        for (int nt = 0; nt < 2; ++nt)
#pragma unroll
          for (int j = 0; j < 4; ++j) {
            int row = mt * 16 + kg * 4 + j, dc = nt * 16 + col;
            if (row < 20)
              aob[swz(row * 256 + hh * 32 + dc, 8)] = f2bf(dav[mt][nt][j]);
          }
    }
    __syncthreads();

    // out projection -> bb fp32
    gemm20<256, 16, M_F32, 8, 8>(aob, 256, ws + AOWO + l * 65536,
                                 aob_b + l * 256, &bb[0][0], nullptr, 256,
                                 nullptr, tid, 0);
    __syncthreads();
    // h = LN1(h + proj)
    ln20(h, hb, &bb[0][0], l1g + l * 256, l1b + l * 256, tid);
    __syncthreads();
    // ff1 + ReLU -> ffb bf16 [20][1024] (two halves)
    gemm20<256, 32, M_BF16RELU, 8, 10>(hb, 256, ws + F1O + l * 262144,
                                       f1b + l * 1024, nullptr, ffb, 1024,
                                       nullptr, tid, 0);
    gemm20<256, 32, M_BF16RELU, 8, 10>(hb, 256, ws + F1O + l * 262144,
                                       f1b + l * 1024, nullptr, ffb, 1024,
                                       nullptr, tid, 32);
    __syncthreads();
    // ff2 -> bb fp32
    gemm20<1024, 16, M_F32, 10, 8>(ffb, 1024, ws + F2O + l * 262144,
                                   f2b + l * 256, &bb[0][0], nullptr, 256,
                                   nullptr, tid, 0);
    __syncthreads();
    // h = LN2(h + ff)
    ln20(h, hb, &bb[0][0], l2g + l * 256, l2b + l * 256, tid);
    __syncthreads();
  }

  // ---- final fc on last token (row 19), fp32: one wave per output
  if (wv < 16) {
    float4 hv = *(const float4*)(&h[19][lane * 4]);
    float4 w4 = *(const float4*)(&fcw[wv * 256 + lane * 4]);
    float s = hv.x * w4.x + hv.y * w4.y + hv.z * w4.z + hv.w * w4.w;
    s = wsum(s);
    if (lane == 0) out[b * 16 + wv] = s + fcb[wv];
  }
}

extern "C" void kernel_launch(void* const* d_in, const int* in_sizes, int n_in,
                              void* d_out, int out_size, void* d_ws, size_t ws_size,
                              hipStream_t stream) {
  const float* x    = (const float*)d_in[0];
  const float* c1w  = (const float*)d_in[1];
  const float* c1b  = (const float*)d_in[2];
  const float* c2w  = (const float*)d_in[3];
  const float* c2b  = (const float*)d_in[4];
  const float* lnfg = (const float*)d_in[5];
  const float* lnfb = (const float*)d_in[6];
  const float* tb   = (const float*)d_in[8];
  const float* tw   = (const float*)d_in[7];
  const float* sw   = (const float*)d_in[9];
  const float* sb   = (const float*)d_in[10];
  const float* aiw  = (const float*)d_in[11];
  const float* aib  = (const float*)d_in[12];
  const float* aow  = (const float*)d_in[13];
  const float* aobb = (const float*)d_in[14];
  const float* l1g  = (const float*)d_in[15];
  const float* l1b  = (const float*)d_in[16];
  const float* f1w  = (const float*)d_in[17];
  const float* f1b  = (const float*)d_in[18];
  const float* f2w  = (const float*)d_in[19];
  const float* f2b  = (const float*)d_in[20];
  const float* l2g  = (const float*)d_in[21];
  const float* l2b  = (const float*)d_in[22];
  const float* fcw  = (const float*)d_in[23];
  const float* fcb  = (const float*)d_in[24];
  float* out = (float*)d_out;
  ushort* ws = (ushort*)d_ws;

  k_cvt<<<4096, 256, 0, stream>>>(c2w, tw, sw, aiw, aow, f1w, f2w, ws);
  aai_main<<<32, NTH, 0, stream>>>(x, c1w, c1b, c2b, lnfg, lnfb, tb, sb, aib,
                                   aobb, l1g, l1b, f1b, f2b, l2g, l2b, fcw,
                                   fcb, ws, out);
}

// Round 7
// 342.175 us; speedup vs baseline: 4.8326x; 1.0996x over previous
//
#include <hip/hip_runtime.h>
#include <math.h>

#define NTH 512

typedef __attribute__((ext_vector_type(8))) short short8;
typedef __attribute__((ext_vector_type(4))) float f32x4;
typedef unsigned short ushort;
typedef unsigned int uint;

#define MFMA16(a, b, c) __builtin_amdgcn_mfma_f32_16x16x32_bf16(a, b, c, 0, 0, 0)

// fp32 -> bf16 round-to-nearest-even
__device__ __forceinline__ ushort f2bf(float f) {
  uint u = __float_as_uint(f);
  u = (u + 0x7FFFu + ((u >> 16) & 1u)) >> 16;
  return (ushort)u;
}

// Flat-index LDS XOR-swizzle (T2): permutes 16B slots within a 128B window.
// Write and read must use the same (idx, sh).
__device__ __forceinline__ int swz(int idx, int sh) {
  return idx ^ (((idx >> sh) & 7) << 3);
}

__device__ __forceinline__ float wsum(float v) {
#pragma unroll
  for (int off = 32; off > 0; off >>= 1) v += __shfl_xor(v, off, 64);
  return v;
}

// ---- weight convert kernel: fp32 inputs -> bf16 in d_ws ------------------
#define W2R 0            // [256][768]  conv2 re-layout: w2r[o][t*256+e] = c2w[o][e*3+t]
#define TWO 196608       // [256][256]
#define SWO 262144       // [256][256]
#define QKVO 327680      // [4][768][256]
#define AOWO 1114112     // [4][256][256]
#define F1O 1376256      // [4][1024][256]
#define F2O 2424832      // [4][256][1024]
#define WTOT 3473408

__global__ void k_cvt(const float* __restrict__ c2w, const float* __restrict__ tw,
                      const float* __restrict__ sw, const float* __restrict__ aiw,
                      const float* __restrict__ aow, const float* __restrict__ f1w,
                      const float* __restrict__ f2w, ushort* __restrict__ ws) {
  for (int i = blockIdx.x * blockDim.x + threadIdx.x; i < WTOT;
       i += gridDim.x * blockDim.x) {
    float v;
    if (i < TWO) {
      int o = i / 768, k = i - o * 768;
      int t = k >> 8, e = k & 255;
      v = c2w[o * 768 + e * 3 + t];
    } else if (i < SWO) v = tw[i - TWO];
    else if (i < QKVO) v = sw[i - SWO];
    else if (i < AOWO) v = aiw[i - QKVO];
    else if (i < F1O)  v = aow[i - AOWO];
    else if (i < F2O)  v = f1w[i - F1O];
    else               v = f2w[i - F2O];
    ws[i] = f2bf(v);
  }
}

// ---- MFMA GEMM: out[20][...] = act(bias + A[20][K] * W[N][K]^T) ----------
// 8 waves, each handling column tiles tile0 + wv + 8*i (i < NTILES/8).
#define M_F32 0
#define M_F32RELU 1
#define M_SINADD 2
#define M_BF16 3
#define M_BF16RELU 4
#define M_QKV 5

template <int KDIM, int NTILES, int MODE, int ASH, int OSH>
__device__ __forceinline__ void gemm20(const ushort* __restrict__ A, int lda,
                                       const ushort* __restrict__ Wg,
                                       const float* __restrict__ bias,
                                       float* __restrict__ outf,
                                       ushort* __restrict__ outb, int ostride,
                                       ushort* __restrict__ vt, int tid,
                                       int tile0) {
  constexpr int NCH = KDIM / 128;
  constexpr int MY = NTILES / 8;
  const int lane = tid & 63;
  const int wv = tid >> 6;  // 0..7
  const int col = lane & 15;
  const int kg = lane >> 4;
  const int r0 = col;
  const int r1c = (16 + col > 19) ? 19 : (16 + col);

  f32x4 acc[MY][2];
#pragma unroll
  for (int i = 0; i < MY; ++i) {
    const float bv = bias[(tile0 + wv + 8 * i) * 16 + col];
#pragma unroll
    for (int mt = 0; mt < 2; ++mt) acc[i][mt] = {bv, bv, bv, bv};
  }

#pragma unroll 2
  for (int kc = 0; kc < NCH; ++kc) {
    short8 af[2][4];
#pragma unroll
    for (int ks = 0; ks < 4; ++ks) {
      const int k0 = kc * 128 + ks * 32 + kg * 8;
      af[0][ks] = *(const short8*)(A + swz(r0 * lda + k0, ASH));
      af[1][ks] = *(const short8*)(A + swz(r1c * lda + k0, ASH));
    }
#pragma unroll
    for (int i = 0; i < MY; ++i) {
      const ushort* wb =
          Wg + (size_t)((tile0 + wv + 8 * i) * 16 + col) * KDIM + kc * 128 +
          kg * 8;
#pragma unroll
      for (int ks = 0; ks < 4; ++ks) {
        short8 bf = *(const short8*)(wb + ks * 32);
        acc[i][0] = MFMA16(af[0][ks], bf, acc[i][0]);
        acc[i][1] = MFMA16(af[1][ks], bf, acc[i][1]);
      }
    }
  }

#pragma unroll
  for (int i = 0; i < MY; ++i) {
    const int og = (tile0 + wv + 8 * i) * 16 + col;
#pragma unroll
    for (int mt = 0; mt < 2; ++mt) {
#pragma unroll
      for (int j = 0; j < 4; ++j) {
        const int row = mt * 16 + kg * 4 + j;
        if (row < 20) {
          float v = acc[i][mt][j];
          if (MODE == M_F32) outf[row * ostride + og] = v;
          if (MODE == M_F32RELU) outf[row * ostride + og] = fmaxf(v, 0.f);
          if (MODE == M_SINADD) outf[row * ostride + og] += sinf(v);
          if (MODE == M_BF16) outb[swz(row * ostride + og, OSH)] = f2bf(v);
          if (MODE == M_BF16RELU)
            outb[swz(row * ostride + og, OSH)] = f2bf(fmaxf(v, 0.f));
          if (MODE == M_QKV) {
            ushort bv = f2bf(v);
            outb[swz(row * ostride + og, OSH)] = bv;
            if (og >= 512) {  // V part -> transposed copy vt[h][dh][token]
              int hh = (og - 512) >> 5, dh = (og - 512) & 31;
              vt[swz(hh * 1024 + dh * 32 + row, 5)] = bv;
            }
          }
        }
      }
    }
  }
}

// in-place LayerNorm over 20 rows of H; optional residual add; bf16 mirror hb
__device__ __forceinline__ void ln20(float (*H)[256], ushort* __restrict__ hb,
                                     const float* __restrict__ add,
                                     const float* __restrict__ g,
                                     const float* __restrict__ bt, int tid) {
  const int lane = tid & 63;
  const int wv = tid >> 6;
  const int d0 = lane * 4;
  for (int r = wv; r < 20; r += 8) {
    float xv[4];
#pragma unroll
    for (int j = 0; j < 4; ++j) {
      xv[j] = H[r][d0 + j];
      if (add) xv[j] += add[r * 256 + d0 + j];
    }
    float m = wsum(xv[0] + xv[1] + xv[2] + xv[3]) * (1.f / 256.f);
    float c0 = xv[0] - m, c1 = xv[1] - m, c2 = xv[2] - m, c3 = xv[3] - m;
    float var = wsum(c0 * c0 + c1 * c1 + c2 * c2 + c3 * c3) * (1.f / 256.f);
    float inv = rsqrtf(var + 1e-5f);
#pragma unroll
    for (int j = 0; j < 4; ++j) {
      float cj = (j == 0 ? c0 : j == 1 ? c1 : j == 2 ? c2 : c3);
      float o = cj * inv * g[d0 + j] + bt[d0 + j];
      H[r][d0 + j] = o;
      hb[swz(r * 256 + d0 + j, 8)] = f2bf(o);
    }
  }
}

// 512 threads = 8 waves = 2 waves/SIMD. Grid is 32 blocks on 256 CUs, so
// inter-block occupancy is irrelevant; launch_bounds(512,2) caps at 256
// VGPRs/wave (128 arch + 128 acc) — R4's proven no-spill budget with 2x its
// latency hiding. 1024-thread blocks forced a 64-arch-VGPR cap -> 26 MB
// scratch spills (R5/R6 WRITE_SIZE).
__global__ __launch_bounds__(NTH, 2) void aai_main(
    const float* __restrict__ x, const float* __restrict__ c1w,
    const float* __restrict__ c1b, const float* __restrict__ c2b,
    const float* __restrict__ lnfg, const float* __restrict__ lnfb,
    const float* __restrict__ tb, const float* __restrict__ sb,
    const float* __restrict__ aib, const float* __restrict__ aob_b,
    const float* __restrict__ l1g, const float* __restrict__ l1b,
    const float* __restrict__ f1b, const float* __restrict__ f2b,
    const float* __restrict__ l2g, const float* __restrict__ l2b,
    const float* __restrict__ fcw, const float* __restrict__ fcb,
    const ushort* __restrict__ ws, float* __restrict__ out) {
  __shared__ float xs[24][16];
  __shared__ float h[20][256];
  __shared__ float bb[20][256];
  __shared__ __align__(16) ushort hb[20 * 256];
  __shared__ __align__(16) ushort qkvb[20 * 768];
  __shared__ __align__(16) ushort big[20480];  // c1[22][256] | {aob,P,vT} | ffb[20][1024]
  __shared__ float scores[8 * 20 * 20];

  const int tid = threadIdx.x;
  const int b = blockIdx.x;
  const int lane = tid & 63;
  const int wv = tid >> 6;
  const int col = lane & 15;
  const int kg = lane >> 4;
  const int r1c = (16 + col > 19) ? 19 : (16 + col);

  ushort* c1u = big;           // [22][256]  (swz sh=8)
  ushort* ffb = big;           // [20][1024] (swz sh=10)
  ushort* aob = big;           // [20][256]  (swz sh=8)
  ushort* Pb = big + 5120;     // [8][20][32] (swz sh=5)
  ushort* vT = big + 10240;    // [8][32][32] (swz sh=5)

  // ---- stage x tail (t = 3977..3999, row 23 = 0)
  for (int i = tid; i < 24 * 16; i += NTH) {
    int r = i >> 4, c = i & 15;
    xs[r][c] = (r < 23) ? x[((size_t)b * 4000 + 3977 + r) * 16 + c] : 0.f;
  }
  __syncthreads();

  // ---- conv1 + ReLU -> c1 bf16 (rows t=3979..3999, row 21 = t=4000 = 0)
  if (tid < 256) {
    const int d = tid;
    const float* wr = c1w + d * 48;
    float acc[21];
    const float bv = c1b[d];
#pragma unroll
    for (int r = 0; r < 21; ++r) acc[r] = bv;
    for (int c = 0; c < 16; ++c) {
      float xv[23];
#pragma unroll
      for (int i = 0; i < 23; ++i) xv[i] = xs[i + 1][c];
      float w0 = wr[c * 3], w1 = wr[c * 3 + 1], w2 = wr[c * 3 + 2];
#pragma unroll
      for (int r = 0; r < 21; ++r)
        acc[r] += xv[r] * w0 + xv[r + 1] * w1 + xv[r + 2] * w2;
    }
#pragma unroll
    for (int r = 0; r < 21; ++r)
      c1u[swz(r * 256 + d, 8)] = f2bf(fmaxf(acc[r], 0.f));
    c1u[swz(21 * 256 + d, 8)] = 0;
  }
  __syncthreads();

  // ---- conv2 + ReLU -> h fp32 (GEMM: A[r][k]=c1_flat[r*256+k], K=768)
  gemm20<768, 16, M_F32RELU, 8, 8>(c1u, 256, ws + W2R, c2b, &h[0][0], nullptr,
                                   256, nullptr, tid, 0);
  __syncthreads();

  // ---- LayerNorm_f
  ln20(h, hb, nullptr, lnfg, lnfb, tid);
  __syncthreads();

  // ---- trend -> bb ; season -> bb += sin(.)
  gemm20<256, 16, M_F32, 8, 8>(hb, 256, ws + TWO, tb, &bb[0][0], nullptr, 256,
                               nullptr, tid, 0);
  __syncthreads();
  gemm20<256, 16, M_SINADD, 8, 8>(hb, 256, ws + SWO, sb, &bb[0][0], nullptr,
                                  256, nullptr, tid, 0);
  __syncthreads();
  for (int i = tid; i < 20 * 256; i += NTH) {
    float v = (&h[0][0])[i] + (&bb[0][0])[i];
    (&h[0][0])[i] = v;
    hb[swz(i, 8)] = f2bf(v);
  }
  __syncthreads();

  // ---- encoder layers
  for (int l = 0; l < 4; ++l) {
    // qkv projection: Q,K tiles 0..31 (two calls); V tiles 32..47 (+ vT).
    gemm20<256, 16, M_BF16, 8, 8>(hb, 256, ws + QKVO + l * 196608,
                                  aib + l * 768, nullptr, qkvb, 768, nullptr,
                                  tid, 0);
    gemm20<256, 16, M_BF16, 8, 8>(hb, 256, ws + QKVO + l * 196608,
                                  aib + l * 768, nullptr, qkvb, 768, nullptr,
                                  tid, 16);
    gemm20<256, 16, M_QKV, 8, 8>(hb, 256, ws + QKVO + l * 196608,
                                 aib + l * 768, nullptr, qkvb, 768, vT, tid,
                                 32);
    // vT pad tokens 20..31 never written by the epilogue -> zero (layer-0 LDS
    // garbage there can be NaN/Inf bf16 and 0*Inf = NaN in the PV MFMA).
    for (int i = tid; i < 8 * 32 * 12; i += NTH) {
      int hh = i / 384, r = i - hh * 384;
      int dh = r / 12, tk = 20 + (r - dh * 12);
      vT[swz(hh * 1024 + dh * 32 + tk, 5)] = 0;
    }
    __syncthreads();

    // scores = Q.K^T / sqrt(32), one head per wave (8 waves = 8 heads)
    {
      const int hh = wv;
      short8 aq[2], bk[2];
      aq[0] = *(const short8*)(qkvb + swz(col * 768 + hh * 32 + kg * 8, 8));
      aq[1] = *(const short8*)(qkvb + swz(r1c * 768 + hh * 32 + kg * 8, 8));
      bk[0] = *(const short8*)(qkvb + swz(col * 768 + 256 + hh * 32 + kg * 8, 8));
      bk[1] = *(const short8*)(qkvb + swz(r1c * 768 + 256 + hh * 32 + kg * 8, 8));
      f32x4 dqk[2][2];
#pragma unroll
      for (int mt = 0; mt < 2; ++mt)
#pragma unroll
        for (int nt = 0; nt < 2; ++nt) {
          dqk[mt][nt] = {0.f, 0.f, 0.f, 0.f};
          dqk[mt][nt] = MFMA16(aq[mt], bk[nt], dqk[mt][nt]);
        }
#pragma unroll
      for (int mt = 0; mt < 2; ++mt)
#pragma unroll
        for (int nt = 0; nt < 2; ++nt)
#pragma unroll
          for (int j = 0; j < 4; ++j) {
            int row = mt * 16 + kg * 4 + j, kj = nt * 16 + col;
            if (row < 20 && kj < 20)
              scores[hh * 400 + row * 20 + kj] =
                  dqk[mt][nt][j] * 0.17677669529663687f;
          }
    }
    __syncthreads();

    // softmax rows -> P bf16 [8][20][32], zero-padded to K=32
    if (tid < 160) {
      const int hh = tid / 20, q = tid - hh * 20;
      const float* row = scores + hh * 400 + q * 20;
      float m = row[0];
#pragma unroll
      for (int j = 1; j < 20; ++j) m = fmaxf(m, row[j]);
      float e[20], s = 0.f;
#pragma unroll
      for (int j = 0; j < 20; ++j) { e[j] = __expf(row[j] - m); s += e[j]; }
      float inv = 1.f / s;
#pragma unroll
      for (int j = 0; j < 20; ++j)
        Pb[swz(hh * 640 + q * 32 + j, 5)] = f2bf(e[j] * inv);
#pragma unroll
      for (int j = 20; j < 32; ++j) Pb[swz(hh * 640 + q * 32 + j, 5)] = 0;
    }
    __syncthreads();

    // O = P @ V per head (one head per wave) via MFMA (K=32) -> aob bf16
    {
      const int hh = wv;
      short8 ap[2], bv[2];
      ap[0] = *(const short8*)(Pb + swz(hh * 640 + col * 32 + kg * 8, 5));
      ap[1] = *(const short8*)(Pb + swz(hh * 640 + r1c * 32 + kg * 8, 5));
      bv[0] = *(const short8*)(vT + swz(hh * 1024 + col * 32 + kg * 8, 5));
      bv[1] = *(const short8*)(vT + swz(hh * 1024 + (16 + col) * 32 + kg * 8, 5));
      f32x4 dav[2][2];
#pragma unroll
      for (int mt = 0; mt < 2; ++mt)
#pragma unroll
        for (int nt = 0; nt < 2; ++nt) {
          dav[mt][nt] = {0.f, 0.f, 0.f, 0.f};
          dav[mt][nt] = MFMA16(ap[mt], bv[nt], dav[mt][nt]);
        }
#pragma unroll
      for (int mt = 0; mt < 2; ++mt)
#pragma unroll
        for (int nt = 0; nt < 2; ++nt)
#pragma unroll
          for (int j = 0; j < 4; ++j) {
            int row = mt * 16 + kg * 4 + j, dc = nt * 16 + col;
            if (row < 20)
              aob[swz(row * 256 + hh * 32 + dc, 8)] = f2bf(dav[mt][nt][j]);
          }
    }
    __syncthreads();

    // out projection -> bb fp32
    gemm20<256, 16, M_F32, 8, 8>(aob, 256, ws + AOWO + l * 65536,
                                 aob_b + l * 256, &bb[0][0], nullptr, 256,
                                 nullptr, tid, 0);
    __syncthreads();
    // h = LN1(h + proj)
    ln20(h, hb, &bb[0][0], l1g + l * 256, l1b + l * 256, tid);
    __syncthreads();
    // ff1 + ReLU -> ffb bf16 [20][1024] (two halves, MY=4 each)
    gemm20<256, 32, M_BF16RELU, 8, 10>(hb, 256, ws + F1O + l * 262144,
                                       f1b + l * 1024, nullptr, ffb, 1024,
                                       nullptr, tid, 0);
    gemm20<256, 32, M_BF16RELU, 8, 10>(hb, 256, ws + F1O + l * 262144,
                                       f1b + l * 1024, nullptr, ffb, 1024,
                                       nullptr, tid, 32);
    __syncthreads();
    // ff2 -> bb fp32
    gemm20<1024, 16, M_F32, 10, 8>(ffb, 1024, ws + F2O + l * 262144,
                                   f2b + l * 256, &bb[0][0], nullptr, 256,
                                   nullptr, tid, 0);
    __syncthreads();
    // h = LN2(h + ff)
    ln20(h, hb, &bb[0][0], l2g + l * 256, l2b + l * 256, tid);
    __syncthreads();
  }

  // ---- final fc on last token (row 19), fp32: 8 waves x 2 outputs
  for (int o = wv; o < 16; o += 8) {
    float4 hv = *(const float4*)(&h[19][lane * 4]);
    float4 w4 = *(const float4*)(&fcw[o * 256 + lane * 4]);
    float s = hv.x * w4.x + hv.y * w4.y + hv.z * w4.z + hv.w * w4.w;
    s = wsum(s);
    if (lane == 0) out[b * 16 + o] = s + fcb[o];
  }
}

extern "C" void kernel_launch(void* const* d_in, const int* in_sizes, int n_in,
                              void* d_out, int out_size, void* d_ws, size_t ws_size,
                              hipStream_t stream) {
  const float* x    = (const float*)d_in[0];
  const float* c1w  = (const float*)d_in[1];
  const float* c1b  = (const float*)d_in[2];
  const float* c2w  = (const float*)d_in[3];
  const float* c2b  = (const float*)d_in[4];
  const float* lnfg = (const float*)d_in[5];
  const float* lnfb = (const float*)d_in[6];
  const float* tw   = (const float*)d_in[7];
  const float* tb   = (const float*)d_in[8];
  const float* sw   = (const float*)d_in[9];
  const float* sb   = (const float*)d_in[10];
  const float* aiw  = (const float*)d_in[11];
  const float* aib  = (const float*)d_in[12];
  const float* aow  = (const float*)d_in[13];
  const float* aobb = (const float*)d_in[14];
  const float* l1g  = (const float*)d_in[15];
  const float* l1b  = (const float*)d_in[16];
  const float* f1w  = (const float*)d_in[17];
  const float* f1b  = (const float*)d_in[18];
  const float* f2w  = (const float*)d_in[19];
  const float* f2b  = (const float*)d_in[20];
  const float* l2g  = (const float*)d_in[21];
  const float* l2b  = (const float*)d_in[22];
  const float* fcw  = (const float*)d_in[23];
  const float* fcb  = (const float*)d_in[24];
  float* out = (float*)d_out;
  ushort* ws = (ushort*)d_ws;

  k_cvt<<<4096, 256, 0, stream>>>(c2w, tw, sw, aiw, aow, f1w, f2w, ws);
  aai_main<<<32, NTH, 0, stream>>>(x, c1w, c1b, c2b, lnfg, lnfb, tb, sb, aib,
                                   aobb, l1g, l1b, f1b, f2b, l2g, l2b, fcw,
                                   fcb, ws, out);
}

// Round 8
// 255.465 us; speedup vs baseline: 6.4729x; 1.3394x over previous
//
#include <hip/hip_runtime.h>
#include <math.h>

#define NTH 512

typedef __attribute__((ext_vector_type(8))) short short8;
typedef __attribute__((ext_vector_type(4))) float f32x4;
typedef unsigned short ushort;
typedef unsigned int uint;

#define MFMA16(a, b, c) __builtin_amdgcn_mfma_f32_16x16x32_bf16(a, b, c, 0, 0, 0)

// fp32 -> bf16 round-to-nearest-even
__device__ __forceinline__ ushort f2bf(float f) {
  uint u = __float_as_uint(f);
  u = (u + 0x7FFFu + ((u >> 16) & 1u)) >> 16;
  return (ushort)u;
}

// Flat-index LDS XOR-swizzle for A-operand tiles (write & read same (idx,sh)).
__device__ __forceinline__ int swz(int idx, int sh) {
  return idx ^ (((idx >> sh) & 7) << 3);
}

__device__ __forceinline__ float wsum(float v) {
#pragma unroll
  for (int off = 32; off > 0; off >>= 1) v += __shfl_xor(v, off, 64);
  return v;
}

// async global->LDS DMA, 16B per lane (lds dst = wave-uniform base + lane*16)
__device__ __forceinline__ void gl_lds16(const ushort* g, ushort* l) {
  __builtin_amdgcn_global_load_lds(
      (const __attribute__((address_space(1))) void*)g,
      (__attribute__((address_space(3))) void*)l, 16, 0, 0);
}

// ---- weight streams in d_ws (bf16, per-wave consumption order) ----------
// Stream layout for a GEMM (NTILES tiles of 16 output cols, KDIM):
//   MY = NTILES/8 tiles per wave (tile = wv + 8*i), NCH = KDIM/128.
//   chunk (1KB = 512 ushorts) = B-fragments for (tile, kc, ks):
//     element (row = (w+8i)*16+col, k = kc*128+ks*32+kg*8+j) at
//     [w][kc][i][ks][lane=kg*16+col][j].
#define S_CONV2 0        // 16 tiles, K=768 (conv2 re-laid: k=t*256+e)
#define S_TREND 196608   // 16 tiles, K=256
#define S_SEASON 262144  // 16 tiles, K=256
#define S_QKV 327680     // 4 layers x 48 tiles, K=256
#define S_AOW 1114112    // 4 x 16 tiles, K=256
#define S_F1 1376256     // 4 x 64 tiles, K=256
#define S_F2 2424832     // 4 x 16 tiles, K=1024
#define WTOT 3473408

template <int MY, int NCH>
__device__ __forceinline__ void dec(int idx, int& row, int& k) {
  int pos = idx & 511, lane = pos >> 3, j = pos & 7;
  int kg = lane >> 4, col = lane & 15;
  int chunk = idx >> 9, ks = chunk & 3, t2 = chunk >> 2;
  int w = t2 / (MY * NCH), r2 = t2 - w * (MY * NCH);
  int kc = r2 / MY, ii = r2 - kc * MY;
  row = (w + 8 * ii) * 16 + col;
  k = kc * 128 + ks * 32 + kg * 8 + j;
}

__global__ void k_cvt(const float* __restrict__ c2w, const float* __restrict__ tw,
                      const float* __restrict__ sw, const float* __restrict__ aiw,
                      const float* __restrict__ aow, const float* __restrict__ f1w,
                      const float* __restrict__ f2w, ushort* __restrict__ ws) {
  for (int i = blockIdx.x * blockDim.x + threadIdx.x; i < WTOT;
       i += gridDim.x * blockDim.x) {
    float v; int row, k;
    if (i < S_TREND) {
      dec<2, 6>(i, row, k);
      int t = k >> 8, e = k & 255;
      v = c2w[row * 768 + e * 3 + t];
    } else if (i < S_SEASON) {
      dec<2, 2>(i - S_TREND, row, k); v = tw[row * 256 + k];
    } else if (i < S_QKV) {
      dec<2, 2>(i - S_SEASON, row, k); v = sw[row * 256 + k];
    } else if (i < S_AOW) {
      int r = i - S_QKV; int l = r / 196608; r -= l * 196608;
      dec<6, 2>(r, row, k); v = aiw[(size_t)l * 196608 + row * 256 + k];
    } else if (i < S_F1) {
      int r = i - S_AOW; int l = r >> 16; r &= 65535;
      dec<2, 2>(r, row, k); v = aow[l * 65536 + row * 256 + k];
    } else if (i < S_F2) {
      int r = i - S_F1; int l = r >> 18; r &= 262143;
      dec<8, 2>(r, row, k); v = f1w[l * 262144 + row * 256 + k];
    } else {
      int r = i - S_F2; int l = r >> 18; r &= 262143;
      dec<2, 8>(r, row, k); v = f2w[l * 262144 + row * 1024 + k];
    }
    ws[i] = f2bf(v);
  }
}

// ---- MFMA GEMM with ring-buffered async B staging -----------------------
#define M_F32 0
#define M_F32RELU 1
#define M_SINADD 2
#define M_BF16RELU 4
#define M_QKV 5

template <int KDIM, int NTILES, int MODE, int ASH, int OSH>
__device__ __forceinline__ void gemm20(const ushort* __restrict__ A, int lda,
                                       const ushort* __restrict__ Wst,
                                       const float* __restrict__ bias,
                                       float* __restrict__ outf,
                                       ushort* __restrict__ outb, int ostride,
                                       ushort* __restrict__ vt,
                                       ushort* __restrict__ ring, int tid) {
  constexpr int NCH = KDIM / 128, MY = NTILES / 8, C = MY * NCH * 4, R = 4;
  const int lane = tid & 63, wv = tid >> 6, col = lane & 15, kg = lane >> 4;
  const int r0c = col, r1c = (16 + col > 19) ? 19 : (16 + col);
  const ushort* ws0 = Wst + (size_t)wv * C * 512 + lane * 8;
  ushort* rw = ring + wv * (R * 512);
  const int lofs = lane * 8;

  // prologue: fill the 4-slot ring
#pragma unroll
  for (int r = 0; r < R; ++r) gl_lds16(ws0 + r * 512, rw + r * 512);

  f32x4 acc[MY][2];
#pragma unroll
  for (int i = 0; i < MY; ++i) {
    acc[i][0] = {0.f, 0.f, 0.f, 0.f};
    acc[i][1] = {0.f, 0.f, 0.f, 0.f};
  }

  int c = 0;
#pragma unroll
  for (int kc = 0; kc < NCH; ++kc) {
    short8 af[2][4];
#pragma unroll
    for (int ks = 0; ks < 4; ++ks) {
      const int k0 = kc * 128 + ks * 32 + kg * 8;
      af[0][ks] = *(const short8*)(A + swz(r0c * lda + k0, ASH));
      af[1][ks] = *(const short8*)(A + swz(r1c * lda + k0, ASH));
    }
#pragma unroll
    for (int i = 0; i < MY; ++i) {
#pragma unroll
      for (int ks = 0; ks < 4; ++ks) {
        if (c + R < C)
          asm volatile("s_waitcnt vmcnt(3)" ::: "memory");
        else if (c + R == C)
          asm volatile("s_waitcnt vmcnt(0)" ::: "memory");
        short8 bf = *(const short8*)(rw + ((c & 3) << 9) + lofs);
        if (c + R < C) gl_lds16(ws0 + (c + R) * 512, rw + ((c & 3) << 9));
        acc[i][0] = MFMA16(af[0][ks], bf, acc[i][0]);
        acc[i][1] = MFMA16(af[1][ks], bf, acc[i][1]);
        ++c;
      }
    }
  }

#pragma unroll
  for (int i = 0; i < MY; ++i) {
    const int og = (wv + 8 * i) * 16 + col;
    const float bv = bias[og];
#pragma unroll
    for (int mt = 0; mt < 2; ++mt) {
#pragma unroll
      for (int j = 0; j < 4; ++j) {
        const int row = mt * 16 + kg * 4 + j;
        if (row < 20) {
          float v = acc[i][mt][j] + bv;
          if (MODE == M_F32) outf[row * ostride + og] = v;
          if (MODE == M_F32RELU) outf[row * ostride + og] = fmaxf(v, 0.f);
          if (MODE == M_SINADD) outf[row * ostride + og] += sinf(v);
          if (MODE == M_BF16RELU)
            outb[swz(row * ostride + og, OSH)] = f2bf(fmaxf(v, 0.f));
          if (MODE == M_QKV) {
            ushort bvu = f2bf(v);
            outb[swz(row * ostride + og, OSH)] = bvu;
            if (og >= 512) {  // V -> transposed copy vt[h][dh][token]
              int hh = (og - 512) >> 5, dh = (og - 512) & 31;
              vt[swz(hh * 1024 + dh * 32 + row, 5)] = bvu;
            }
          }
        }
      }
    }
  }
}

// in-place LayerNorm over 20 rows of H; optional residual add; bf16 mirror hb
__device__ __forceinline__ void ln20(float (*H)[256], ushort* __restrict__ hb,
                                     const float* __restrict__ add,
                                     const float* __restrict__ g,
                                     const float* __restrict__ bt, int tid) {
  const int lane = tid & 63;
  const int wv = tid >> 6;
  const int d0 = lane * 4;
  for (int r = wv; r < 20; r += 8) {
    float xv[4];
#pragma unroll
    for (int j = 0; j < 4; ++j) {
      xv[j] = H[r][d0 + j];
      if (add) xv[j] += add[r * 256 + d0 + j];
    }
    float m = wsum(xv[0] + xv[1] + xv[2] + xv[3]) * (1.f / 256.f);
    float c0 = xv[0] - m, c1 = xv[1] - m, c2 = xv[2] - m, c3 = xv[3] - m;
    float var = wsum(c0 * c0 + c1 * c1 + c2 * c2 + c3 * c3) * (1.f / 256.f);
    float inv = rsqrtf(var + 1e-5f);
#pragma unroll
    for (int j = 0; j < 4; ++j) {
      float cj = (j == 0 ? c0 : j == 1 ? c1 : j == 2 ? c2 : c3);
      float o = cj * inv * g[d0 + j] + bt[d0 + j];
      H[r][d0 + j] = o;
      hb[swz(r * 256 + d0 + j, 8)] = f2bf(o);
    }
  }
}

__global__ __launch_bounds__(NTH, 2) void aai_main(
    const float* __restrict__ x, const float* __restrict__ c1w,
    const float* __restrict__ c1b, const float* __restrict__ c2b,
    const float* __restrict__ lnfg, const float* __restrict__ lnfb,
    const float* __restrict__ tb, const float* __restrict__ sb,
    const float* __restrict__ aib, const float* __restrict__ aob_b,
    const float* __restrict__ l1g, const float* __restrict__ l1b,
    const float* __restrict__ f1b, const float* __restrict__ f2b,
    const float* __restrict__ l2g, const float* __restrict__ l2b,
    const float* __restrict__ fcw, const float* __restrict__ fcb,
    const ushort* __restrict__ ws, float* __restrict__ out) {
  __shared__ float xs[24][16];
  __shared__ float h[20][256];
  __shared__ float bb[20][256];          // also overlays attn scores (f32)
  __shared__ __align__(16) ushort hb[20 * 256];
  __shared__ __align__(16) ushort qkvb[20 * 768];
  __shared__ __align__(16) ushort big[20480];  // c1/ffb | {aob,P,vT}
  __shared__ __align__(16) ushort ring[8 * 4 * 512];  // B-staging rings

  const int tid = threadIdx.x;
  const int b = blockIdx.x;
  const int lane = tid & 63;
  const int wv = tid >> 6;
  const int col = lane & 15;
  const int kg = lane >> 4;
  const int r1c = (16 + col > 19) ? 19 : (16 + col);

  ushort* c1u = big;           // [22][256]  (swz sh=8)
  ushort* ffb = big;           // [20][1024] (swz sh=10)
  ushort* aob = big;           // [20][256]  (swz sh=8)
  ushort* Pb = big + 5120;     // [8][20][32] (swz sh=5)
  ushort* vT = big + 10240;    // [8][32][32] (swz sh=5)
  float* scores = &bb[0][0];   // [8][20][20] overlay (bb dead in attn phase)

  // ---- stage x tail (t = 3977..3999, row 23 = 0)
  for (int i = tid; i < 24 * 16; i += NTH) {
    int r = i >> 4, c = i & 15;
    xs[r][c] = (r < 23) ? x[((size_t)b * 4000 + 3977 + r) * 16 + c] : 0.f;
  }
  __syncthreads();

  // ---- conv1 + ReLU -> c1 bf16 (rows t=3979..3999, row 21 = t=4000 = 0)
  if (tid < 256) {
    const int d = tid;
    const float* wr = c1w + d * 48;
    float acc[21];
    const float bv = c1b[d];
#pragma unroll
    for (int r = 0; r < 21; ++r) acc[r] = bv;
    for (int c = 0; c < 16; ++c) {
      float xv[23];
#pragma unroll
      for (int i = 0; i < 23; ++i) xv[i] = xs[i + 1][c];
      float w0 = wr[c * 3], w1 = wr[c * 3 + 1], w2 = wr[c * 3 + 2];
#pragma unroll
      for (int r = 0; r < 21; ++r)
        acc[r] += xv[r] * w0 + xv[r + 1] * w1 + xv[r + 2] * w2;
    }
#pragma unroll
    for (int r = 0; r < 21; ++r)
      c1u[swz(r * 256 + d, 8)] = f2bf(fmaxf(acc[r], 0.f));
    c1u[swz(21 * 256 + d, 8)] = 0;
  }
  __syncthreads();

  // ---- conv2 + ReLU -> h fp32 (GEMM: A[r][k]=c1_flat[r*256+k], K=768)
  gemm20<768, 16, M_F32RELU, 8, 8>(c1u, 256, ws + S_CONV2, c2b, &h[0][0],
                                   nullptr, 256, nullptr, ring, tid);
  __syncthreads();

  // ---- LayerNorm_f
  ln20(h, hb, nullptr, lnfg, lnfb, tid);
  __syncthreads();

  // ---- trend -> bb ; season -> bb += sin(.)
  gemm20<256, 16, M_F32, 8, 8>(hb, 256, ws + S_TREND, tb, &bb[0][0], nullptr,
                               256, nullptr, ring, tid);
  __syncthreads();
  gemm20<256, 16, M_SINADD, 8, 8>(hb, 256, ws + S_SEASON, sb, &bb[0][0],
                                  nullptr, 256, nullptr, ring, tid);
  __syncthreads();
  for (int i = tid; i < 20 * 256; i += NTH) {
    float v = (&h[0][0])[i] + (&bb[0][0])[i];
    (&h[0][0])[i] = v;
    hb[swz(i, 8)] = f2bf(v);
  }
  __syncthreads();

  // ---- encoder layers
  for (int l = 0; l < 4; ++l) {
    // qkv projection: 48 tiles in one call (MY=6) -> qkvb bf16 + vT
    gemm20<256, 48, M_QKV, 8, 8>(hb, 256, ws + S_QKV + l * 196608,
                                 aib + l * 768, nullptr, qkvb, 768, vT, ring,
                                 tid);
    // vT pad tokens 20..31 never written by the epilogue -> zero (layer-0 LDS
    // garbage there can be NaN/Inf bf16 and 0*Inf = NaN in the PV MFMA).
    for (int i = tid; i < 8 * 32 * 12; i += NTH) {
      int hh = i / 384, r = i - hh * 384;
      int dh = r / 12, tk = 20 + (r - dh * 12);
      vT[swz(hh * 1024 + dh * 32 + tk, 5)] = 0;
    }
    __syncthreads();

    // scores = Q.K^T / sqrt(32), one head per wave (8 waves = 8 heads)
    {
      const int hh = wv;
      short8 aq[2], bk[2];
      aq[0] = *(const short8*)(qkvb + swz(col * 768 + hh * 32 + kg * 8, 8));
      aq[1] = *(const short8*)(qkvb + swz(r1c * 768 + hh * 32 + kg * 8, 8));
      bk[0] = *(const short8*)(qkvb + swz(col * 768 + 256 + hh * 32 + kg * 8, 8));
      bk[1] = *(const short8*)(qkvb + swz(r1c * 768 + 256 + hh * 32 + kg * 8, 8));
      f32x4 dqk[2][2];
#pragma unroll
      for (int mt = 0; mt < 2; ++mt)
#pragma unroll
        for (int nt = 0; nt < 2; ++nt) {
          dqk[mt][nt] = {0.f, 0.f, 0.f, 0.f};
          dqk[mt][nt] = MFMA16(aq[mt], bk[nt], dqk[mt][nt]);
        }
#pragma unroll
      for (int mt = 0; mt < 2; ++mt)
#pragma unroll
        for (int nt = 0; nt < 2; ++nt)
#pragma unroll
          for (int j = 0; j < 4; ++j) {
            int row = mt * 16 + kg * 4 + j, kj = nt * 16 + col;
            if (row < 20 && kj < 20)
              scores[hh * 400 + row * 20 + kj] =
                  dqk[mt][nt][j] * 0.17677669529663687f;
          }
    }
    __syncthreads();

    // softmax rows -> P bf16 [8][20][32], zero-padded to K=32
    if (tid < 160) {
      const int hh = tid / 20, q = tid - hh * 20;
      const float* row = scores + hh * 400 + q * 20;
      float m = row[0];
#pragma unroll
      for (int j = 1; j < 20; ++j) m = fmaxf(m, row[j]);
      float e[20], s = 0.f;
#pragma unroll
      for (int j = 0; j < 20; ++j) { e[j] = __expf(row[j] - m); s += e[j]; }
      float inv = 1.f / s;
#pragma unroll
      for (int j = 0; j < 20; ++j)
        Pb[swz(hh * 640 + q * 32 + j, 5)] = f2bf(e[j] * inv);
#pragma unroll
      for (int j = 20; j < 32; ++j) Pb[swz(hh * 640 + q * 32 + j, 5)] = 0;
    }
    __syncthreads();

    // O = P @ V per head (one head per wave) via MFMA (K=32) -> aob bf16
    {
      const int hh = wv;
      short8 ap[2], bv[2];
      ap[0] = *(const short8*)(Pb + swz(hh * 640 + col * 32 + kg * 8, 5));
      ap[1] = *(const short8*)(Pb + swz(hh * 640 + r1c * 32 + kg * 8, 5));
      bv[0] = *(const short8*)(vT + swz(hh * 1024 + col * 32 + kg * 8, 5));
      bv[1] = *(const short8*)(vT + swz(hh * 1024 + (16 + col) * 32 + kg * 8, 5));
      f32x4 dav[2][2];
#pragma unroll
      for (int mt = 0; mt < 2; ++mt)
#pragma unroll
        for (int nt = 0; nt < 2; ++nt) {
          dav[mt][nt] = {0.f, 0.f, 0.f, 0.f};
          dav[mt][nt] = MFMA16(ap[mt], bv[nt], dav[mt][nt]);
        }
#pragma unroll
      for (int mt = 0; mt < 2; ++mt)
#pragma unroll
        for (int nt = 0; nt < 2; ++nt)
#pragma unroll
          for (int j = 0; j < 4; ++j) {
            int row = mt * 16 + kg * 4 + j, dc = nt * 16 + col;
            if (row < 20)
              aob[swz(row * 256 + hh * 32 + dc, 8)] = f2bf(dav[mt][nt][j]);
          }
    }
    __syncthreads();

    // out projection -> bb fp32 (scores region dead by now)
    gemm20<256, 16, M_F32, 8, 8>(aob, 256, ws + S_AOW + l * 65536,
                                 aob_b + l * 256, &bb[0][0], nullptr, 256,
                                 nullptr, ring, tid);
    __syncthreads();
    // h = LN1(h + proj)
    ln20(h, hb, &bb[0][0], l1g + l * 256, l1b + l * 256, tid);
    __syncthreads();
    // ff1 + ReLU -> ffb bf16 [20][1024] (one call, MY=8)
    gemm20<256, 64, M_BF16RELU, 8, 10>(hb, 256, ws + S_F1 + l * 262144,
                                       f1b + l * 1024, nullptr, ffb, 1024,
                                       nullptr, ring, tid);
    __syncthreads();
    // ff2 -> bb fp32
    gemm20<1024, 16, M_F32, 10, 8>(ffb, 1024, ws + S_F2 + l * 262144,
                                   f2b + l * 256, &bb[0][0], nullptr, 256,
                                   nullptr, ring, tid);
    __syncthreads();
    // h = LN2(h + ff)
    ln20(h, hb, &bb[0][0], l2g + l * 256, l2b + l * 256, tid);
    __syncthreads();
  }

  // ---- final fc on last token (row 19), fp32: 8 waves x 2 outputs
  for (int o = wv; o < 16; o += 8) {
    float4 hv = *(const float4*)(&h[19][lane * 4]);
    float4 w4 = *(const float4*)(&fcw[o * 256 + lane * 4]);
    float s = hv.x * w4.x + hv.y * w4.y + hv.z * w4.z + hv.w * w4.w;
    s = wsum(s);
    if (lane == 0) out[b * 16 + o] = s + fcb[o];
  }
}

extern "C" void kernel_launch(void* const* d_in, const int* in_sizes, int n_in,
                              void* d_out, int out_size, void* d_ws, size_t ws_size,
                              hipStream_t stream) {
  const float* x    = (const float*)d_in[0];
  const float* c1w  = (const float*)d_in[1];
  const float* c1b  = (const float*)d_in[2];
  const float* c2w  = (const float*)d_in[3];
  const float* c2b  = (const float*)d_in[4];
  const float* lnfg = (const float*)d_in[5];
  const float* lnfb = (const float*)d_in[6];
  const float* tw   = (const float*)d_in[7];
  const float* tb   = (const float*)d_in[8];
  const float* sw   = (const float*)d_in[9];
  const float* sb   = (const float*)d_in[10];
  const float* aiw  = (const float*)d_in[11];
  const float* aib  = (const float*)d_in[12];
  const float* aow  = (const float*)d_in[13];
  const float* aobb = (const float*)d_in[14];
  const float* l1g  = (const float*)d_in[15];
  const float* l1b  = (const float*)d_in[16];
  const float* f1w  = (const float*)d_in[17];
  const float* f1b  = (const float*)d_in[18];
  const float* f2w  = (const float*)d_in[19];
  const float* f2b  = (const float*)d_in[20];
  const float* l2g  = (const float*)d_in[21];
  const float* l2b  = (const float*)d_in[22];
  const float* fcw  = (const float*)d_in[23];
  const float* fcb  = (const float*)d_in[24];
  float* out = (float*)d_out;
  ushort* ws = (ushort*)d_ws;

  k_cvt<<<4096, 256, 0, stream>>>(c2w, tw, sw, aiw, aow, f1w, f2w, ws);
  aai_main<<<32, NTH, 0, stream>>>(x, c1w, c1b, c2b, lnfg, lnfb, tb, sb, aib,
                                   aobb, l1g, l1b, f1b, f2b, l2g, l2b, fcw,
                                   fcb, ws, out);
}

// Round 10
// 226.598 us; speedup vs baseline: 7.2975x; 1.1274x over previous
//
#include <hip/hip_runtime.h>
#include <math.h>

#define NTH 512

typedef __attribute__((ext_vector_type(8))) short short8;
typedef __attribute__((ext_vector_type(4))) float f32x4;
typedef unsigned short ushort;
typedef unsigned int uint;

#define MFMA16(a, b, c) __builtin_amdgcn_mfma_f32_16x16x32_bf16(a, b, c, 0, 0, 0)

// fp32 -> bf16 round-to-nearest-even
__device__ __forceinline__ ushort f2bf(float f) {
  uint u = __float_as_uint(f);
  u = (u + 0x7FFFu + ((u >> 16) & 1u)) >> 16;
  return (ushort)u;
}

// Flat-index LDS XOR-swizzle for A-operand tiles (write & read same (idx,sh)).
__device__ __forceinline__ int swz(int idx, int sh) {
  return idx ^ (((idx >> sh) & 7) << 3);
}

__device__ __forceinline__ float wsum(float v) {
#pragma unroll
  for (int off = 32; off > 0; off >>= 1) v += __shfl_xor(v, off, 64);
  return v;
}

// async global->LDS DMA, 16B per lane (lds dst = wave-uniform base + lane*16)
__device__ __forceinline__ void gl_lds16(const ushort* g, ushort* l) {
  __builtin_amdgcn_global_load_lds(
      (const __attribute__((address_space(1))) void*)g,
      (__attribute__((address_space(3))) void*)l, 16, 0, 0);
}

// ---- weight streams in d_ws (bf16, per-wave consumption order) ----------
// chunk (1KB = 512 ushorts) = B-fragments for (tile, kc, ks):
//   [w][kc][i][ks][lane=kg*16+col][j]  (tile = wv + 8*i, k = kc*128+ks*32+kg*8+j)
#define S_CONV2 0        // 16 tiles, K=768 (conv2 re-laid: k=t*256+e)
#define S_TREND 196608   // 16 tiles, K=256
#define S_SEASON 262144  // 16 tiles, K=256
#define S_QKV 327680     // 4 layers x 48 tiles, K=256
#define S_AOW 1114112    // 4 x 16 tiles, K=256
#define S_F1 1376256     // 4 x 64 tiles, K=256
#define S_F2 2424832     // 4 x 16 tiles, K=1024
#define WTOT 3473408

template <int MY, int NCH>
__device__ __forceinline__ void dec(int idx, int& row, int& k) {
  int pos = idx & 511, lane = pos >> 3, j = pos & 7;
  int kg = lane >> 4, col = lane & 15;
  int chunk = idx >> 9, ks = chunk & 3, t2 = chunk >> 2;
  int w = t2 / (MY * NCH), r2 = t2 - w * (MY * NCH);
  int kc = r2 / MY, ii = r2 - kc * MY;
  row = (w + 8 * ii) * 16 + col;
  k = kc * 128 + ks * 32 + kg * 8 + j;
}

__global__ void k_cvt(const float* __restrict__ c2w, const float* __restrict__ tw,
                      const float* __restrict__ sw, const float* __restrict__ aiw,
                      const float* __restrict__ aow, const float* __restrict__ f1w,
                      const float* __restrict__ f2w, ushort* __restrict__ ws) {
  for (int i = blockIdx.x * blockDim.x + threadIdx.x; i < WTOT;
       i += gridDim.x * blockDim.x) {
    float v; int row, k;
    if (i < S_TREND) {
      dec<2, 6>(i, row, k);
      int t = k >> 8, e = k & 255;
      v = c2w[row * 768 + e * 3 + t];
    } else if (i < S_SEASON) {
      dec<2, 2>(i - S_TREND, row, k); v = tw[row * 256 + k];
    } else if (i < S_QKV) {
      dec<2, 2>(i - S_SEASON, row, k); v = sw[row * 256 + k];
    } else if (i < S_AOW) {
      int r = i - S_QKV; int l = r / 196608; r -= l * 196608;
      dec<6, 2>(r, row, k); v = aiw[(size_t)l * 196608 + row * 256 + k];
    } else if (i < S_F1) {
      int r = i - S_AOW; int l = r >> 16; r &= 65535;
      dec<2, 2>(r, row, k); v = aow[l * 65536 + row * 256 + k];
    } else if (i < S_F2) {
      int r = i - S_F1; int l = r >> 18; r &= 262143;
      dec<8, 2>(r, row, k); v = f1w[l * 262144 + row * 256 + k];
    } else {
      int r = i - S_F2; int l = r >> 18; r &= 262143;
      dec<2, 8>(r, row, k); v = f2w[l * 262144 + row * 1024 + k];
    }
    ws[i] = f2bf(v);
  }
}

// ---- MFMA GEMM with ring-buffered async B staging -----------------------
// Ring consume is inline-asm ds_read_b128 (hides DMA->read aliasing from the
// compiler; R8's auto vmcnt(0) collapsed the ring). CRITICAL ordering (R9
// bug): the ds_read must RETIRE (lgkmcnt(0)) BEFORE the DMA that overwrites
// the same slot is issued — ds_read (LDS pipe) and global_load_lds write
// (VMEM pipe) have no mutual ordering. Manual counted vmcnt(3) is the only
// DMA gate; bias is pre-loaded + drained before the prologue so vmcnt counts
// see only DMA ops.
#define M_F32 0
#define M_F32RELU 1
#define M_SINADD 2
#define M_BF16RELU 4
#define M_QKV 5

template <int KDIM, int NTILES, int MODE, int ASH, int OSH>
__device__ __forceinline__ void gemm20(const ushort* __restrict__ A, int lda,
                                       const ushort* __restrict__ Wst,
                                       const float* __restrict__ bias,
                                       float* __restrict__ outf,
                                       ushort* __restrict__ outb, int ostride,
                                       ushort* __restrict__ vt,
                                       ushort* __restrict__ ring, int tid) {
  constexpr int NCH = KDIM / 128, MY = NTILES / 8, C = MY * NCH * 4, R = 4;
  const int lane = tid & 63, wv = tid >> 6, col = lane & 15, kg = lane >> 4;
  const int r0c = col, r1c = (16 + col > 19) ? 19 : (16 + col);
  const ushort* ws0 = Wst + (size_t)wv * C * 512 + lane * 8;
  ushort* rw = ring + wv * (R * 512);
  const int lofs = lane * 8;

  // bias pre-load + drain (keeps manual vmcnt counts DMA-only)
  float bv[MY];
#pragma unroll
  for (int i = 0; i < MY; ++i) bv[i] = bias[(wv + 8 * i) * 16 + col];
  asm volatile("s_waitcnt vmcnt(0)" ::: "memory");

  // prologue: fill the 4-slot ring
#pragma unroll
  for (int r = 0; r < R; ++r) gl_lds16(ws0 + r * 512, rw + r * 512);

  f32x4 acc[MY][2];
#pragma unroll
  for (int i = 0; i < MY; ++i) {
    acc[i][0] = {bv[i], bv[i], bv[i], bv[i]};
    acc[i][1] = {bv[i], bv[i], bv[i], bv[i]};
  }

  int c = 0;
#pragma unroll
  for (int kc = 0; kc < NCH; ++kc) {
    short8 af[2][4];
#pragma unroll
    for (int ks = 0; ks < 4; ++ks) {
      const int k0 = kc * 128 + ks * 32 + kg * 8;
      af[0][ks] = *(const short8*)(A + swz(r0c * lda + k0, ASH));
      af[1][ks] = *(const short8*)(A + swz(r1c * lda + k0, ASH));
    }
#pragma unroll
    for (int i = 0; i < MY; ++i) {
#pragma unroll
      for (int ks = 0; ks < 4; ++ks) {
        if (c + R < C)
          asm volatile("s_waitcnt vmcnt(3)" ::: "memory");
        else if (c + R == C)
          asm volatile("s_waitcnt vmcnt(0)" ::: "memory");
        short8 bf;
        asm volatile("ds_read_b128 %0, %1"
                     : "=v"(bf)
                     : "v"((uint)(size_t)(rw + ((c & 3) << 9) + lofs))
                     : "memory");
        // retire the read BEFORE overwriting the slot (R9 race fix)
        asm volatile("s_waitcnt lgkmcnt(0)" ::: "memory");
        __builtin_amdgcn_sched_barrier(0);
        if (c + R < C) gl_lds16(ws0 + (c + R) * 512, rw + ((c & 3) << 9));
        acc[i][0] = MFMA16(af[0][ks], bf, acc[i][0]);
        acc[i][1] = MFMA16(af[1][ks], bf, acc[i][1]);
        ++c;
      }
    }
  }

#pragma unroll
  for (int i = 0; i < MY; ++i) {
    const int og = (wv + 8 * i) * 16 + col;
#pragma unroll
    for (int mt = 0; mt < 2; ++mt) {
#pragma unroll
      for (int j = 0; j < 4; ++j) {
        const int row = mt * 16 + kg * 4 + j;
        if (row < 20) {
          float v = acc[i][mt][j];
          if (MODE == M_F32) outf[row * ostride + og] = v;
          if (MODE == M_F32RELU) outf[row * ostride + og] = fmaxf(v, 0.f);
          if (MODE == M_SINADD) outf[row * ostride + og] += sinf(v);
          if (MODE == M_BF16RELU)
            outb[swz(row * ostride + og, OSH)] = f2bf(fmaxf(v, 0.f));
          if (MODE == M_QKV) {
            ushort bvu = f2bf(v);
            outb[swz(row * ostride + og, OSH)] = bvu;
            if (og >= 512) {  // V -> transposed copy vt[h][dh][token]
              int hh = (og - 512) >> 5, dh = (og - 512) & 31;
              vt[swz(hh * 1024 + dh * 32 + row, 5)] = bvu;
            }
          }
        }
      }
    }
  }
}

// in-place LayerNorm over 20 rows of H; optional residual add; bf16 mirror hb
__device__ __forceinline__ void ln20(float (*H)[256], ushort* __restrict__ hb,
                                     const float* __restrict__ add,
                                     const float* __restrict__ g,
                                     const float* __restrict__ bt, int tid) {
  const int lane = tid & 63;
  const int wv = tid >> 6;
  const int d0 = lane * 4;
  for (int r = wv; r < 20; r += 8) {
    float xv[4];
#pragma unroll
    for (int j = 0; j < 4; ++j) {
      xv[j] = H[r][d0 + j];
      if (add) xv[j] += add[r * 256 + d0 + j];
    }
    float m = wsum(xv[0] + xv[1] + xv[2] + xv[3]) * (1.f / 256.f);
    float c0 = xv[0] - m, c1 = xv[1] - m, c2 = xv[2] - m, c3 = xv[3] - m;
    float var = wsum(c0 * c0 + c1 * c1 + c2 * c2 + c3 * c3) * (1.f / 256.f);
    float inv = rsqrtf(var + 1e-5f);
#pragma unroll
    for (int j = 0; j < 4; ++j) {
      float cj = (j == 0 ? c0 : j == 1 ? c1 : j == 2 ? c2 : c3);
      float o = cj * inv * g[d0 + j] + bt[d0 + j];
      H[r][d0 + j] = o;
      hb[swz(r * 256 + d0 + j, 8)] = f2bf(o);
    }
  }
}

__global__ __launch_bounds__(NTH, 2) void aai_main(
    const float* __restrict__ x, const float* __restrict__ c1w,
    const float* __restrict__ c1b, const float* __restrict__ c2b,
    const float* __restrict__ lnfg, const float* __restrict__ lnfb,
    const float* __restrict__ tb, const float* __restrict__ sb,
    const float* __restrict__ aib, const float* __restrict__ aob_b,
    const float* __restrict__ l1g, const float* __restrict__ l1b,
    const float* __restrict__ f1b, const float* __restrict__ f2b,
    const float* __restrict__ l2g, const float* __restrict__ l2b,
    const float* __restrict__ fcw, const float* __restrict__ fcb,
    const ushort* __restrict__ ws, float* __restrict__ out) {
  __shared__ float xs[24][16];
  __shared__ float h[20][256];
  __shared__ float bb[20][256];          // also overlays attn scores (f32)
  __shared__ __align__(16) ushort hb[20 * 256];
  __shared__ __align__(16) ushort qkvb[20 * 768];
  __shared__ __align__(16) ushort big[20480];  // c1/ffb | {aob,P,vT}
  __shared__ __align__(16) ushort ring[8 * 4 * 512];  // B-staging rings

  const int tid = threadIdx.x;
  const int b = blockIdx.x;
  const int lane = tid & 63;
  const int wv = tid >> 6;
  const int col = lane & 15;
  const int kg = lane >> 4;
  const int r1c = (16 + col > 19) ? 19 : (16 + col);

  ushort* c1u = big;           // [22][256]  (swz sh=8)
  ushort* ffb = big;           // [20][1024] (swz sh=10)
  ushort* aob = big;           // [20][256]  (swz sh=8)
  ushort* Pb = big + 5120;     // [8][20][32] (swz sh=5)
  ushort* vT = big + 10240;    // [8][32][32] (swz sh=5)
  float* scores = &bb[0][0];   // [8][20][20] overlay (bb dead in attn phase)

  // ---- stage x tail (t = 3977..3999, row 23 = 0)
  for (int i = tid; i < 24 * 16; i += NTH) {
    int r = i >> 4, c = i & 15;
    xs[r][c] = (r < 23) ? x[((size_t)b * 4000 + 3977 + r) * 16 + c] : 0.f;
  }
  __syncthreads();

  // ---- conv1 + ReLU -> c1 bf16 (rows t=3979..3999, row 21 = t=4000 = 0)
  if (tid < 256) {
    const int d = tid;
    const float* wr = c1w + d * 48;
    float acc[21];
    const float bv = c1b[d];
#pragma unroll
    for (int r = 0; r < 21; ++r) acc[r] = bv;
    for (int c = 0; c < 16; ++c) {
      float xv[23];
#pragma unroll
      for (int i = 0; i < 23; ++i) xv[i] = xs[i + 1][c];
      float w0 = wr[c * 3], w1 = wr[c * 3 + 1], w2 = wr[c * 3 + 2];
#pragma unroll
      for (int r = 0; r < 21; ++r)
        acc[r] += xv[r] * w0 + xv[r + 1] * w1 + xv[r + 2] * w2;
    }
#pragma unroll
    for (int r = 0; r < 21; ++r)
      c1u[swz(r * 256 + d, 8)] = f2bf(fmaxf(acc[r], 0.f));
    c1u[swz(21 * 256 + d, 8)] = 0;
  }
  __syncthreads();

  // ---- conv2 + ReLU -> h fp32 (GEMM: A[r][k]=c1_flat[r*256+k], K=768)
  gemm20<768, 16, M_F32RELU, 8, 8>(c1u, 256, ws + S_CONV2, c2b, &h[0][0],
                                   nullptr, 256, nullptr, ring, tid);
  __syncthreads();

  // ---- LayerNorm_f
  ln20(h, hb, nullptr, lnfg, lnfb, tid);
  __syncthreads();

  // ---- trend -> bb ; season -> bb += sin(.)
  gemm20<256, 16, M_F32, 8, 8>(hb, 256, ws + S_TREND, tb, &bb[0][0], nullptr,
                               256, nullptr, ring, tid);
  __syncthreads();
  gemm20<256, 16, M_SINADD, 8, 8>(hb, 256, ws + S_SEASON, sb, &bb[0][0],
                                  nullptr, 256, nullptr, ring, tid);
  __syncthreads();
  for (int i = tid; i < 20 * 256; i += NTH) {
    float v = (&h[0][0])[i] + (&bb[0][0])[i];
    (&h[0][0])[i] = v;
    hb[swz(i, 8)] = f2bf(v);
  }
  __syncthreads();

  // ---- encoder layers
  for (int l = 0; l < 4; ++l) {
    // qkv projection: 48 tiles in one call (MY=6) -> qkvb bf16 + vT
    gemm20<256, 48, M_QKV, 8, 8>(hb, 256, ws + S_QKV + l * 196608,
                                 aib + l * 768, nullptr, qkvb, 768, vT, ring,
                                 tid);
    // vT pad tokens 20..31 never written by the epilogue -> zero (layer-0 LDS
    // garbage there can be NaN/Inf bf16 and 0*Inf = NaN in the PV MFMA).
    for (int i = tid; i < 8 * 32 * 12; i += NTH) {
      int hh = i / 384, r = i - hh * 384;
      int dh = r / 12, tk = 20 + (r - dh * 12);
      vT[swz(hh * 1024 + dh * 32 + tk, 5)] = 0;
    }
    __syncthreads();

    // scores = Q.K^T / sqrt(32), one head per wave (8 waves = 8 heads)
    {
      const int hh = wv;
      short8 aq[2], bk[2];
      aq[0] = *(const short8*)(qkvb + swz(col * 768 + hh * 32 + kg * 8, 8));
      aq[1] = *(const short8*)(qkvb + swz(r1c * 768 + hh * 32 + kg * 8, 8));
      bk[0] = *(const short8*)(qkvb + swz(col * 768 + 256 + hh * 32 + kg * 8, 8));
      bk[1] = *(const short8*)(qkvb + swz(r1c * 768 + 256 + hh * 32 + kg * 8, 8));
      f32x4 dqk[2][2];
#pragma unroll
      for (int mt = 0; mt < 2; ++mt)
#pragma unroll
        for (int nt = 0; nt < 2; ++nt) {
          dqk[mt][nt] = {0.f, 0.f, 0.f, 0.f};
          dqk[mt][nt] = MFMA16(aq[mt], bk[nt], dqk[mt][nt]);
        }
#pragma unroll
      for (int mt = 0; mt < 2; ++mt)
#pragma unroll
        for (int nt = 0; nt < 2; ++nt)
#pragma unroll
          for (int j = 0; j < 4; ++j) {
            int row = mt * 16 + kg * 4 + j, kj = nt * 16 + col;
            if (row < 20 && kj < 20)
              scores[hh * 400 + row * 20 + kj] =
                  dqk[mt][nt][j] * 0.17677669529663687f;
          }
    }
    __syncthreads();

    // softmax rows -> P bf16 [8][20][32], zero-padded to K=32
    if (tid < 160) {
      const int hh = tid / 20, q = tid - hh * 20;
      const float* row = scores + hh * 400 + q * 20;
      float m = row[0];
#pragma unroll
      for (int j = 1; j < 20; ++j) m = fmaxf(m, row[j]);
      float e[20], s = 0.f;
#pragma unroll
      for (int j = 0; j < 20; ++j) { e[j] = __expf(row[j] - m); s += e[j]; }
      float inv = 1.f / s;
#pragma unroll
      for (int j = 0; j < 20; ++j)
        Pb[swz(hh * 640 + q * 32 + j, 5)] = f2bf(e[j] * inv);
#pragma unroll
      for (int j = 20; j < 32; ++j) Pb[swz(hh * 640 + q * 32 + j, 5)] = 0;
    }
    __syncthreads();

    // O = P @ V per head (one head per wave) via MFMA (K=32) -> aob bf16
    {
      const int hh = wv;
      short8 ap[2], bvv[2];
      ap[0] = *(const short8*)(Pb + swz(hh * 640 + col * 32 + kg * 8, 5));
      ap[1] = *(const short8*)(Pb + swz(hh * 640 + r1c * 32 + kg * 8, 5));
      bvv[0] = *(const short8*)(vT + swz(hh * 1024 + col * 32 + kg * 8, 5));
      bvv[1] = *(const short8*)(vT + swz(hh * 1024 + (16 + col) * 32 + kg * 8, 5));
      f32x4 dav[2][2];
#pragma unroll
      for (int mt = 0; mt < 2; ++mt)
#pragma unroll
        for (int nt = 0; nt < 2; ++nt) {
          dav[mt][nt] = {0.f, 0.f, 0.f, 0.f};
          dav[mt][nt] = MFMA16(ap[mt], bvv[nt], dav[mt][nt]);
        }
#pragma unroll
      for (int mt = 0; mt < 2; ++mt)
#pragma unroll
        for (int nt = 0; nt < 2; ++nt)
#pragma unroll
          for (int j = 0; j < 4; ++j) {
            int row = mt * 16 + kg * 4 + j, dc = nt * 16 + col;
            if (row < 20)
              aob[swz(row * 256 + hh * 32 + dc, 8)] = f2bf(dav[mt][nt][j]);
          }
    }
    __syncthreads();

    // out projection -> bb fp32 (scores region dead by now)
    gemm20<256, 16, M_F32, 8, 8>(aob, 256, ws + S_AOW + l * 65536,
                                 aob_b + l * 256, &bb[0][0], nullptr, 256,
                                 nullptr, ring, tid);
    __syncthreads();
    // h = LN1(h + proj)
    ln20(h, hb, &bb[0][0], l1g + l * 256, l1b + l * 256, tid);
    __syncthreads();
    // ff1 + ReLU -> ffb bf16 [20][1024] (one call, MY=8)
    gemm20<256, 64, M_BF16RELU, 8, 10>(hb, 256, ws + S_F1 + l * 262144,
                                       f1b + l * 1024, nullptr, ffb, 1024,
                                       nullptr, ring, tid);
    __syncthreads();
    // ff2 -> bb fp32
    gemm20<1024, 16, M_F32, 10, 8>(ffb, 1024, ws + S_F2 + l * 262144,
                                   f2b + l * 256, &bb[0][0], nullptr, 256,
                                   nullptr, ring, tid);
    __syncthreads();
    // h = LN2(h + ff)
    ln20(h, hb, &bb[0][0], l2g + l * 256, l2b + l * 256, tid);
    __syncthreads();
  }

  // ---- final fc on last token (row 19), fp32: 8 waves x 2 outputs
  for (int o = wv; o < 16; o += 8) {
    float4 hv = *(const float4*)(&h[19][lane * 4]);
    float4 w4 = *(const float4*)(&fcw[o * 256 + lane * 4]);
    float s = hv.x * w4.x + hv.y * w4.y + hv.z * w4.z + hv.w * w4.w;
    s = wsum(s);
    if (lane == 0) out[b * 16 + o] = s + fcb[o];
  }
}

extern "C" void kernel_launch(void* const* d_in, const int* in_sizes, int n_in,
                              void* d_out, int out_size, void* d_ws, size_t ws_size,
                              hipStream_t stream) {
  const float* x    = (const float*)d_in[0];
  const float* c1w  = (const float*)d_in[1];
  const float* c1b  = (const float*)d_in[2];
  const float* c2w  = (const float*)d_in[3];
  const float* c2b  = (const float*)d_in[4];
  const float* lnfg = (const float*)d_in[5];
  const float* lnfb = (const float*)d_in[6];
  const float* tw   = (const float*)d_in[7];
  const float* tb   = (const float*)d_in[8];
  const float* sw   = (const float*)d_in[9];
  const float* sb   = (const float*)d_in[10];
  const float* aiw  = (const float*)d_in[11];
  const float* aib  = (const float*)d_in[12];
  const float* aow  = (const float*)d_in[13];
  const float* aobb = (const float*)d_in[14];
  const float* l1g  = (const float*)d_in[15];
  const float* l1b  = (const float*)d_in[16];
  const float* f1w  = (const float*)d_in[17];
  const float* f1b  = (const float*)d_in[18];
  const float* f2w  = (const float*)d_in[19];
  const float* f2b  = (const float*)d_in[20];
  const float* l2g  = (const float*)d_in[21];
  const float* l2b  = (const float*)d_in[22];
  const float* fcw  = (const float*)d_in[23];
  const float* fcb  = (const float*)d_in[24];
  float* out = (float*)d_out;
  ushort* ws = (ushort*)d_ws;

  k_cvt<<<4096, 256, 0, stream>>>(c2w, tw, sw, aiw, aow, f1w, f2w, ws);
  aai_main<<<32, NTH, 0, stream>>>(x, c1w, c1b, c2b, lnfg, lnfb, tb, sb, aib,
                                   aobb, l1g, l1b, f1b, f2b, l2g, l2b, fcw,
                                   fcb, ws, out);
}